// Round 13
// baseline (1262.709 us; speedup 1.0000x reference)
//
#include <hip/hip_runtime.h>

#define SS   2048
#define DD   2560
#define HH   32
#define DHH  80
#define DPAD 96
#define NII  10240
#define NTOK 4096

typedef __attribute__((ext_vector_type(8))) __bf16 bf16x8;
typedef __attribute__((ext_vector_type(4))) float  f32x4;

__device__ __forceinline__ float bf2f(unsigned short h) {
  union { unsigned u; float f; } c; c.u = ((unsigned)h) << 16; return c.f;
}
__device__ __forceinline__ unsigned short f2bf(float f) {
  union { float f; unsigned u; } c; c.f = f;
  unsigned r = c.u + 0x7FFFu + ((c.u >> 16) & 1u);
  return (unsigned short)(r >> 16);
}

__device__ __forceinline__ void gl_lds16(const void* gptr, void* lptr) {
  __builtin_amdgcn_global_load_lds((__attribute__((address_space(1))) void*)gptr,
                                   (__attribute__((address_space(3))) void*)lptr,
                                   16, 0, 0);
}

// ---------------- weight transpose: W[K][N] fp32 -> Wt[N][K] bf16 ----------------
__global__ __launch_bounds__(256) void wt_transpose(const float* __restrict__ W,
                                                    unsigned short* __restrict__ Wt,
                                                    int K, int N) {
  __shared__ float tile[32][33];
  const int tx = threadIdx.x & 31, ty = threadIdx.x >> 5;
  const int n0 = blockIdx.x * 32, k0 = blockIdx.y * 32;
#pragma unroll
  for (int i = 0; i < 32; i += 8)
    tile[ty + i][tx] = W[(size_t)(k0 + ty + i) * N + n0 + tx];
  __syncthreads();
#pragma unroll
  for (int i = 0; i < 32; i += 8)
    Wt[(size_t)(n0 + ty + i) * K + k0 + tx] = f2bf(tile[tx][ty + i]);
}

// ---------------- LayerNorm: fp32 in -> bf16 out ----------------
__global__ __launch_bounds__(256) void ln_kernel(const float* __restrict__ X,
                                                 const float* __restrict__ G,
                                                 const float* __restrict__ Bb,
                                                 unsigned short* __restrict__ Xo) {
  const int row = blockIdx.x;
  const float4* xr = (const float4*)(X + (size_t)row * DD);
  float s = 0.f, ss = 0.f;
  for (int i = threadIdx.x; i < DD / 4; i += 256) {
    float4 v = xr[i];
    s  += v.x + v.y + v.z + v.w;
    ss += v.x * v.x + v.y * v.y + v.z * v.z + v.w * v.w;
  }
#pragma unroll
  for (int o = 32; o > 0; o >>= 1) { s += __shfl_down(s, o, 64); ss += __shfl_down(ss, o, 64); }
  __shared__ float red[8];
  const int w = threadIdx.x >> 6;
  if ((threadIdx.x & 63) == 0) { red[w] = s; red[4 + w] = ss; }
  __syncthreads();
  if (threadIdx.x == 0) {
    float ts  = red[0] + red[1] + red[2] + red[3];
    float tss = red[4] + red[5] + red[6] + red[7];
    float mu  = ts * (1.f / DD);
    float var = tss * (1.f / DD) - mu * mu;
    red[0] = mu; red[1] = rsqrtf(var + 1e-5f);
  }
  __syncthreads();
  const float mu = red[0], rstd = red[1];
  const float4* gr = (const float4*)G;
  const float4* br = (const float4*)Bb;
  for (int i = threadIdx.x; i < DD / 4; i += 256) {
    float4 v = xr[i], g = gr[i], b = br[i];
    ushort4 o;
    o.x = f2bf((v.x - mu) * rstd * g.x + b.x);
    o.y = f2bf((v.y - mu) * rstd * g.y + b.y);
    o.z = f2bf((v.z - mu) * rstd * g.z + b.z);
    o.w = f2bf((v.w - mu) * rstd * g.w + b.w);
    *(ushort4*)&Xo[(size_t)row * DD + i * 4] = o;
  }
}

// ---------------- RoPE + head-layout ----------------
__global__ __launch_bounds__(256) void rope_kernel(const unsigned short* __restrict__ qkv,
                                                   unsigned short* __restrict__ Qp,
                                                   unsigned short* __restrict__ Kp,
                                                   unsigned short* __restrict__ Vt) {
  const int tok = blockIdx.x;
  const int b = tok / SS, s = tok % SS;
  __shared__ float cs[16], sn[16];
  if (threadIdx.x < 16) {
    float inv = powf(10000.f, -(float)threadIdx.x / 16.f);
    float ang = (float)s * inv;
    cs[threadIdx.x] = cosf(ang);
    sn[threadIdx.x] = sinf(ang);
  }
  __syncthreads();
  const unsigned short* row = qkv + (size_t)tok * (3 * DD);
  for (int idx = threadIdx.x; idx < 2 * HH * DPAD; idx += 256) {
    const int which = idx / (HH * DPAD);
    const int rrem  = idx % (HH * DPAD);
    const int h = rrem / DPAD, d = rrem % DPAD;
    float val = 0.f;
    if (d < DHH) {
      const unsigned short* base = row + which * DD + h * DHH;
      if (d < 16) {
        float x1 = bf2f(base[d]), x2 = bf2f(base[d + 16]);
        val = x1 * cs[d] - x2 * sn[d];
      } else if (d < 32) {
        int i2 = d - 16;
        float x1 = bf2f(base[i2]), x2 = bf2f(base[d]);
        val = x2 * cs[i2] + x1 * sn[i2];
      } else {
        val = bf2f(base[d]);
      }
    }
    unsigned short* outp = which ? Kp : Qp;
    outp[(((size_t)b * HH + h) * SS + s) * DPAD + d] = f2bf(val);
  }
  for (int idx = threadIdx.x; idx < DD; idx += 256) {
    const int h = idx / DHH, d = idx % DHH;
    Vt[(((size_t)b * HH + h) * DHH + d) * SS + s] = row[2 * DD + idx];
  }
}

// ---------------- flash attention (causal): 2 waves/block, 32 q-rows/wave, KVBLK=64 ----------------
__global__ __launch_bounds__(128) void attn_kernel(const unsigned short* __restrict__ Qp,
                                                   const unsigned short* __restrict__ Kp,
                                                   const unsigned short* __restrict__ Vt,
                                                   unsigned short* __restrict__ O) {
  const int bid = blockIdx.x;
  const int bh = bid & 63;
  const int p = 31 - (bid >> 6);        // heavy first (LPT)
  const int w = threadIdx.x >> 6;
  const int tile = p * 2 + w;
  const int lane = threadIdx.x & 63;
  const int lr = lane & 15, lg = lane >> 4;
  const int q0 = tile * 32;
  const unsigned short* Qh = Qp + (size_t)bh * SS * DPAD;
  const unsigned short* Kh = Kp + (size_t)bh * SS * DPAD;
  const unsigned short* Vh = Vt + (size_t)bh * DHH * SS;
  __shared__ __align__(16) char Plds[2][2][2048];

  bf16x8 qf[2][3];
#pragma unroll
  for (int g = 0; g < 2; ++g)
#pragma unroll
    for (int c = 0; c < 3; ++c)
      qf[g][c] = *(const bf16x8*)&Qh[(size_t)(q0 + g * 16 + lr) * DPAD + c * 32 + lg * 8];

  f32x4 oacc[2][5];
#pragma unroll
  for (int g = 0; g < 2; ++g)
#pragma unroll
    for (int d = 0; d < 5; ++d) oacc[g][d] = (f32x4){0.f, 0.f, 0.f, 0.f};
  float mrow[2][4], lrow[2][4];
#pragma unroll
  for (int g = 0; g < 2; ++g)
#pragma unroll
    for (int r = 0; r < 4; ++r) { mrow[g][r] = -1e30f; lrow[g][r] = 0.f; }

  const float scl = 0.11180339887498949f;
  const int nt = (q0 + 31) / 64 + 1;
  for (int t = 0; t < nt; ++t) {
    const int kv0 = t * 64;
    f32x4 s[2][4];
#pragma unroll
    for (int g = 0; g < 2; ++g)
#pragma unroll
      for (int j = 0; j < 4; ++j) s[g][j] = (f32x4){0.f, 0.f, 0.f, 0.f};
#pragma unroll
    for (int c = 0; c < 3; ++c) {
      bf16x8 kf[4];
#pragma unroll
      for (int j = 0; j < 4; ++j)
        kf[j] = *(const bf16x8*)&Kh[(size_t)(kv0 + j * 16 + lr) * DPAD + c * 32 + lg * 8];
#pragma unroll
      for (int g = 0; g < 2; ++g)
#pragma unroll
        for (int j = 0; j < 4; ++j)
          s[g][j] = __builtin_amdgcn_mfma_f32_16x16x32_bf16(qf[g][c], kf[j], s[g][j], 0, 0, 0);
    }
    float pv[2][4][4], mx[2][4];
    bool need = false;
#pragma unroll
    for (int g = 0; g < 2; ++g) {
#pragma unroll
      for (int r = 0; r < 4; ++r) {
        const int qr = q0 + g * 16 + lg * 4 + r;
        float m = -1e30f;
#pragma unroll
        for (int j = 0; j < 4; ++j) {
          float a = (kv0 + j * 16 + lr > qr) ? -1e30f : s[g][j][r] * scl;
          pv[g][j][r] = a;
          m = fmaxf(m, a);
        }
#pragma unroll
        for (int mk = 1; mk < 16; mk <<= 1) m = fmaxf(m, __shfl_xor(m, mk, 64));
        mx[g][r] = m;
        need = need || (m > mrow[g][r] + 8.f);
      }
    }
    if (__ballot(need)) {
#pragma unroll
      for (int g = 0; g < 2; ++g)
#pragma unroll
        for (int r = 0; r < 4; ++r) {
          float mnew = fmaxf(mrow[g][r], mx[g][r]);
          float resc = __expf(mrow[g][r] - mnew);
          lrow[g][r] *= resc;
#pragma unroll
          for (int d = 0; d < 5; ++d) oacc[g][d][r] *= resc;
          mrow[g][r] = mnew;
        }
    }
#pragma unroll
    for (int g = 0; g < 2; ++g) {
      char* Pb = Plds[w][g];
#pragma unroll
      for (int r = 0; r < 4; ++r) {
        const int row = lg * 4 + r;
        const int swz = (row & 7) << 4;
        float rs = 0.f;
#pragma unroll
        for (int j = 0; j < 4; ++j) {
          float pj = __expf(pv[g][j][r] - mrow[g][r]);
          rs += pj;
          *(unsigned short*)(Pb + row * 128 + (((j * 16 + lr) * 2) ^ swz)) = f2bf(pj);
        }
#pragma unroll
        for (int mk = 1; mk < 16; mk <<= 1) rs += __shfl_xor(rs, mk, 64);
        lrow[g][r] += rs;
      }
    }
    asm volatile("s_waitcnt lgkmcnt(0)" ::: "memory");
    const int rswz = (lr & 7) << 4;
    bf16x8 pa[2][2];
#pragma unroll
    for (int g = 0; g < 2; ++g) {
      pa[g][0] = *(const bf16x8*)(Plds[w][g] + lr * 128 + ((lg * 16) ^ rswz));
      pa[g][1] = *(const bf16x8*)(Plds[w][g] + lr * 128 + ((64 + lg * 16) ^ rswz));
    }
#pragma unroll
    for (int d = 0; d < 5; ++d) {
      bf16x8 v0 = *(const bf16x8*)&Vh[(size_t)(d * 16 + lr) * SS + kv0 + lg * 8];
      bf16x8 v1 = *(const bf16x8*)&Vh[(size_t)(d * 16 + lr) * SS + kv0 + 32 + lg * 8];
#pragma unroll
      for (int g = 0; g < 2; ++g) {
        oacc[g][d] = __builtin_amdgcn_mfma_f32_16x16x32_bf16(pa[g][0], v0, oacc[g][d], 0, 0, 0);
        oacc[g][d] = __builtin_amdgcn_mfma_f32_16x16x32_bf16(pa[g][1], v1, oacc[g][d], 0, 0, 0);
      }
    }
  }
  const int b = bh >> 5, h = bh & 31;
#pragma unroll
  for (int g = 0; g < 2; ++g)
#pragma unroll
    for (int r = 0; r < 4; ++r) {
      const int qr = q0 + g * 16 + lg * 4 + r;
      const float inv = 1.f / lrow[g][r];
#pragma unroll
      for (int d = 0; d < 5; ++d)
        O[(size_t)(b * SS + qr) * DD + h * DHH + d * 16 + lr] = f2bf(oacc[g][d][r] * inv);
    }
}

__device__ __forceinline__ float gelu_f(float x) {
  float x3 = x * x * x;
  return 0.5f * x * (1.f + tanhf(0.7978845608028654f * (x + 0.044715f * x3)));
}

// ---------------- 256x256 GEMM: 8 waves, BK=64, 8-phase counted-vmcnt; optional split-K ----------------
// MODE 0: bf16 C+bias ; MODE 2: bf16 gelu(C+bias) ; MODE 3: fp32 C+bias+bf16(addb)+addf ;
// MODE 4: fp32 raw partial (split-K; dst = Cout + s*M*N, Koff = s*Kcnt).
// bid = s*tps + inner; inner column-major (by = inner % nby) for A-panel L2 reuse.
template <int MODE>
__global__ __launch_bounds__(512, 2) void gemm256(const unsigned short* __restrict__ A,
                                                  const unsigned short* __restrict__ Bt,
                                                  const float* __restrict__ bias,
                                                  void* __restrict__ Cout,
                                                  const unsigned short* __restrict__ addb,
                                                  const float* __restrict__ addf,
                                                  int M, int N, int K, int nby,
                                                  int Kcnt, int tps) {
  __shared__ __align__(16) char lds[131072];

  const int bid = blockIdx.x;
  const int s = bid / tps;
  const int inner = bid % tps;
  const int by = inner % nby, bx = inner / nby;
  const int m0 = by * 256, n0 = bx * 256;

  const int tid = threadIdx.x;
  const int w = tid >> 6, lane = tid & 63;
  const int lr = lane & 15, lg = lane >> 4;
  const int wm = w >> 2, wn = w & 3;

  const int srow = w * 16 + (lane >> 3);
  const int scol = ((lane & 7) ^ ((lane >> 3) & 7)) * 8;
  const unsigned short* pA = A  + (size_t)(m0 + srow) * K + scol + (size_t)s * Kcnt;
  const unsigned short* pB = Bt + (size_t)(n0 + srow) * K + scol + (size_t)s * Kcnt;
  const int wdst = w * 2048;

  const int rdA = wm * 16384 + lr * 128;
  const int rdB = 65536 + (wn >> 1) * 16384 + ((wn & 1) * 64 + lr) * 128;
  const int sl0 = ((lg) ^ (lr & 7)) << 4;
  const int sl1 = ((4 + lg) ^ (lr & 7)) << 4;

  f32x4 acc[8][4];
#pragma unroll
  for (int i = 0; i < 8; ++i)
#pragma unroll
    for (int j = 0; j < 4; ++j) acc[i][j] = (f32x4){0.f, 0.f, 0.f, 0.f};

  const int nt = Kcnt >> 6;  // even for all uses (40 / 80 / 160)

#define RA(BUF, m, kh) (*(const bf16x8*)(lds + (BUF) + rdA + (m) * 2048 + ((kh) ? sl1 : sl0)))
#define RB(BUF, n, kh) (*(const bf16x8*)(lds + (BUF) + rdB + (n) * 2048 + ((kh) ? sl1 : sl0)))
#define STGA(dt, h, DST)                                                       \
  { const unsigned short* s_ = pA + (size_t)(dt) * 64 + (size_t)(h) * 128 * K; \
    gl_lds16(s_,                 lds + (DST) + wdst);                          \
    gl_lds16(s_ + (size_t)8 * K, lds + (DST) + wdst + 1024); }
#define STGB(dt, h, DST)                                                       \
  { const unsigned short* s_ = pB + (size_t)(dt) * 64 + (size_t)(h) * 128 * K; \
    gl_lds16(s_,                 lds + 65536 + (DST) + wdst);                  \
    gl_lds16(s_ + (size_t)8 * K, lds + 65536 + (DST) + wdst + 1024); }
#define BARR __builtin_amdgcn_s_barrier()
#define MFMA8x2(AV, BV, MB, NB)                                              \
  __builtin_amdgcn_s_setprio(1);                                             \
  _Pragma("unroll") for (int kh_ = 0; kh_ < 2; ++kh_)                        \
  _Pragma("unroll") for (int m_ = 0; m_ < 4; ++m_)                           \
  _Pragma("unroll") for (int n_ = 0; n_ < 2; ++n_)                           \
    acc[(MB) + m_][(NB) + n_] = __builtin_amdgcn_mfma_f32_16x16x32_bf16(     \
        AV[m_][kh_], BV[n_][kh_], acc[(MB) + m_][(NB) + n_], 0, 0, 0);       \
  __builtin_amdgcn_s_setprio(0);

  STGA(0, 0, 0);
  STGA(0, 1, 16384);
  STGB(0, 0, 0);
  STGB(0, 1, 16384);
  STGA(1, 0, 32768);
  STGA(1, 1, 32768 + 16384);
  STGB(1, 0, 32768);
  asm volatile("s_waitcnt vmcnt(6)" ::: "memory");
  BARR;
  __builtin_amdgcn_sched_barrier(0);

  for (int t = 0; t < nt; t += 2) {
    const bool more = (t + 2 < nt);
    bf16x8 avL[4][2], avH[4][2], bvL[2][2], bvH[2][2];

#pragma unroll
    for (int m_ = 0; m_ < 4; ++m_) { avL[m_][0] = RA(0, m_, 0); avL[m_][1] = RA(0, m_, 1); }
#pragma unroll
    for (int n_ = 0; n_ < 2; ++n_) { bvL[n_][0] = RB(0, n_, 0); bvL[n_][1] = RB(0, n_, 1); }
    STGB(1, 1, 32768 + 16384);
    BARR;
    MFMA8x2(avL, bvL, 0, 0);
    BARR;
#pragma unroll
    for (int m_ = 0; m_ < 4; ++m_) { avH[m_][0] = RA(0, 4 + m_, 0); avH[m_][1] = RA(0, 4 + m_, 1); }
    BARR;
    MFMA8x2(avH, bvL, 4, 0);
    BARR;
#pragma unroll
    for (int n_ = 0; n_ < 2; ++n_) { bvH[n_][0] = RB(0, 2 + n_, 0); bvH[n_][1] = RB(0, 2 + n_, 1); }
    if (more) STGA(2, 0, 0);
    BARR;
    MFMA8x2(avH, bvH, 4, 2);
    BARR;
    if (more) STGA(2, 1, 16384);
    BARR;
    MFMA8x2(avL, bvH, 0, 2);
    if (more) { asm volatile("s_waitcnt vmcnt(4)" ::: "memory"); }
    else      { asm volatile("s_waitcnt vmcnt(0)" ::: "memory"); }
    BARR;
    __builtin_amdgcn_sched_barrier(0);

#pragma unroll
    for (int m_ = 0; m_ < 4; ++m_) { avL[m_][0] = RA(32768, m_, 0); avL[m_][1] = RA(32768, m_, 1); }
#pragma unroll
    for (int n_ = 0; n_ < 2; ++n_) { bvL[n_][0] = RB(32768, n_, 0); bvL[n_][1] = RB(32768, n_, 1); }
    if (more) STGB(2, 0, 0);
    BARR;
    MFMA8x2(avL, bvL, 0, 0);
    BARR;
#pragma unroll
    for (int m_ = 0; m_ < 4; ++m_) { avH[m_][0] = RA(32768, 4 + m_, 0); avH[m_][1] = RA(32768, 4 + m_, 1); }
    if (more) STGB(2, 1, 16384);
    BARR;
    MFMA8x2(avH, bvL, 4, 0);
    BARR;
#pragma unroll
    for (int n_ = 0; n_ < 2; ++n_) { bvH[n_][0] = RB(32768, 2 + n_, 0); bvH[n_][1] = RB(32768, 2 + n_, 1); }
    if (more) STGA(3, 0, 32768);
    BARR;
    MFMA8x2(avH, bvH, 4, 2);
    BARR;
    if (more) { STGA(3, 1, 32768 + 16384); STGB(3, 0, 32768); }
    BARR;
    MFMA8x2(avL, bvH, 0, 2);
    if (more) { asm volatile("s_waitcnt vmcnt(6)" ::: "memory"); }
    BARR;
    __builtin_amdgcn_sched_barrier(0);

    pA += 128; pB += 128;
  }
#undef RA
#undef RB
#undef STGA
#undef STGB
#undef BARR
#undef MFMA8x2

  // epilogue
  float* pdst = (MODE == 4) ? ((float*)Cout + (size_t)s * M * N) : (float*)Cout;
#pragma unroll
  for (int m = 0; m < 8; ++m) {
    const int rb = m0 + wm * 128 + m * 16 + lg * 4;
#pragma unroll
    for (int n = 0; n < 4; ++n) {
      const int col = n0 + wn * 64 + n * 16 + lr;
      const float bv = (MODE == 4) ? 0.f : bias[col];
#pragma unroll
      for (int r = 0; r < 4; ++r) {
        const size_t idx = (size_t)(rb + r) * N + col;
        float v = acc[m][n][r] + bv;
        if (MODE == 2) v = gelu_f(v);
        if (MODE == 3) {
          ((float*)Cout)[idx] = v + bf2f(addb[idx]) + addf[idx];
        } else if (MODE == 4) {
          pdst[idx] = v;
        } else {
          ((unsigned short*)Cout)[idx] = f2bf(v);
        }
      }
    }
  }
}

// ---------------- fc2 split-K reduce: out = P0 + P1 + bias + bf16(addb) + addf ----------------
__global__ __launch_bounds__(256) void fc2_reduce(const float* __restrict__ P0,
                                                  const float* __restrict__ P1,
                                                  const float* __restrict__ bias,
                                                  const unsigned short* __restrict__ addb,
                                                  const float* __restrict__ addf,
                                                  float* __restrict__ out) {
  const size_t total = (size_t)NTOK * DD / 4;
  for (size_t i = (size_t)blockIdx.x * 256 + threadIdx.x; i < total; i += (size_t)gridDim.x * 256) {
    float4 a = ((const float4*)P0)[i];
    float4 b = ((const float4*)P1)[i];
    const int col = (int)((i * 4) % DD);
    float4 bi = *(const float4*)&bias[col];
    ushort4 ab = ((const ushort4*)addb)[i];
    float4 af = ((const float4*)addf)[i];
    float4 r;
    r.x = a.x + b.x + bi.x + bf2f(ab.x) + af.x;
    r.y = a.y + b.y + bi.y + bf2f(ab.y) + af.y;
    r.z = a.z + b.z + bi.z + bf2f(ab.z) + af.z;
    r.w = a.w + b.w + bi.w + bf2f(ab.w) + af.w;
    ((float4*)out)[i] = r;
  }
}

extern "C" void kernel_launch(void* const* d_in, const int* in_sizes, int n_in,
                              void* d_out, int out_size, void* d_ws, size_t ws_size,
                              hipStream_t stream) {
  (void)in_sizes; (void)n_in; (void)out_size; (void)ws_size;
  const float* hidden = (const float*)d_in[1];
  const float* ln_g = (const float*)d_in[2];
  const float* ln_b = (const float*)d_in[3];
  const float* wqkv = (const float*)d_in[4];
  const float* bqkv = (const float*)d_in[5];
  const float* wout = (const float*)d_in[6];
  const float* bout = (const float*)d_in[7];
  const float* wfc1 = (const float*)d_in[8];
  const float* bfc1 = (const float*)d_in[9];
  const float* wfc2 = (const float*)d_in[10];
  const float* bfc2 = (const float*)d_in[11];
  float* out = (float*)d_out;

  char* ws = (char*)d_ws;
  size_t off = 0;
  auto alloc = [&](size_t bytes) -> void* {
    void* p = ws + off;
    off += (bytes + 255) & ~(size_t)255;
    return p;
  };
  unsigned short* wqkvT = (unsigned short*)alloc((size_t)3 * DD * DD * 2);
  unsigned short* woutT = (unsigned short*)alloc((size_t)DD * DD * 2);
  unsigned short* wfc1T = (unsigned short*)alloc((size_t)NII * DD * 2);
  unsigned short* wfc2T = (unsigned short*)alloc((size_t)DD * NII * 2);
  unsigned short* xln   = (unsigned short*)alloc((size_t)NTOK * DD * 2);
  unsigned short* regA  = (unsigned short*)alloc((size_t)NTOK * NII * 2);  // qkv, then h1
  unsigned short* Qp    = (unsigned short*)alloc((size_t)2 * HH * SS * DPAD * 2);  // then attn_proj
  unsigned short* Kp    = (unsigned short*)alloc((size_t)2 * HH * SS * DPAD * 2);
  unsigned short* Vt    = (unsigned short*)alloc((size_t)2 * HH * DHH * SS * 2);
  unsigned short* Obuf  = (unsigned short*)alloc((size_t)NTOK * DD * 2);
  unsigned short* qkvbuf   = regA;
  unsigned short* h1       = regA;
  unsigned short* attnproj = Qp;
  // fc2 split-K partials (2 x 4096x2560 fp32 = 84 MB) alias the wqkvT/woutT/wfc1T region
  // (104.8 MB, all consumed before fc2 runs; transposes rewrite them every launch).
  float* fc2part = (float*)ws;

  wt_transpose<<<dim3(3 * DD / 32, DD / 32), 256, 0, stream>>>(wqkv, wqkvT, DD, 3 * DD);
  wt_transpose<<<dim3(DD / 32, DD / 32), 256, 0, stream>>>(wout, woutT, DD, DD);
  wt_transpose<<<dim3(NII / 32, DD / 32), 256, 0, stream>>>(wfc1, wfc1T, DD, NII);
  wt_transpose<<<dim3(DD / 32, NII / 32), 256, 0, stream>>>(wfc2, wfc2T, NII, DD);
  ln_kernel<<<NTOK, 256, 0, stream>>>(hidden, ln_g, ln_b, xln);
  {
    const int tps = (3 * DD / 256) * (NTOK / 256);
    gemm256<0><<<dim3(tps), 512, 0, stream>>>(
        xln, wqkvT, bqkv, qkvbuf, nullptr, nullptr, NTOK, 3 * DD, DD, NTOK / 256, DD, tps);
  }
  rope_kernel<<<NTOK, 256, 0, stream>>>(qkvbuf, Qp, Kp, Vt);
  attn_kernel<<<dim3(2048), 128, 0, stream>>>(Qp, Kp, Vt, Obuf);
  {
    const int tps = (DD / 256) * (NTOK / 256);
    gemm256<0><<<dim3(tps), 512, 0, stream>>>(
        Obuf, woutT, bout, attnproj, nullptr, nullptr, NTOK, DD, DD, NTOK / 256, DD, tps);
  }
  {
    const int tps = (NII / 256) * (NTOK / 256);
    gemm256<2><<<dim3(tps), 512, 0, stream>>>(
        xln, wfc1T, bfc1, h1, nullptr, nullptr, NTOK, NII, DD, NTOK / 256, DD, tps);
  }
  {
    const int tps = (DD / 256) * (NTOK / 256);  // 160 tiles per split
    gemm256<4><<<dim3(2 * tps), 512, 0, stream>>>(
        h1, wfc2T, nullptr, fc2part, nullptr, nullptr, NTOK, DD, NII, NTOK / 256, NII / 2, tps);
  }
  fc2_reduce<<<dim3(2048), 256, 0, stream>>>(
      fc2part, fc2part + (size_t)NTOK * DD, bfc2, attnproj, hidden, out);
}

// Round 14
// 1223.626 us; speedup vs baseline: 1.0319x; 1.0319x over previous
//
#include <hip/hip_runtime.h>

#define SS   2048
#define DD   2560
#define HH   32
#define DHH  80
#define DPAD 96
#define NII  10240
#define NTOK 4096

typedef __attribute__((ext_vector_type(8))) __bf16 bf16x8;
typedef __attribute__((ext_vector_type(4))) float  f32x4;

__device__ __forceinline__ float bf2f(unsigned short h) {
  union { unsigned u; float f; } c; c.u = ((unsigned)h) << 16; return c.f;
}
__device__ __forceinline__ unsigned short f2bf(float f) {
  union { float f; unsigned u; } c; c.f = f;
  unsigned r = c.u + 0x7FFFu + ((c.u >> 16) & 1u);
  return (unsigned short)(r >> 16);
}

__device__ __forceinline__ void gl_lds16(const void* gptr, void* lptr) {
  __builtin_amdgcn_global_load_lds((__attribute__((address_space(1))) void*)gptr,
                                   (__attribute__((address_space(3))) void*)lptr,
                                   16, 0, 0);
}

// ---------------- weight transpose: W[K][N] fp32 -> Wt[N][K] bf16 ----------------
__global__ __launch_bounds__(256) void wt_transpose(const float* __restrict__ W,
                                                    unsigned short* __restrict__ Wt,
                                                    int K, int N) {
  __shared__ float tile[32][33];
  const int tx = threadIdx.x & 31, ty = threadIdx.x >> 5;
  const int n0 = blockIdx.x * 32, k0 = blockIdx.y * 32;
#pragma unroll
  for (int i = 0; i < 32; i += 8)
    tile[ty + i][tx] = W[(size_t)(k0 + ty + i) * N + n0 + tx];
  __syncthreads();
#pragma unroll
  for (int i = 0; i < 32; i += 8)
    Wt[(size_t)(n0 + ty + i) * K + k0 + tx] = f2bf(tile[tx][ty + i]);
}

// ---------------- LayerNorm: fp32 in -> bf16 out ----------------
__global__ __launch_bounds__(256) void ln_kernel(const float* __restrict__ X,
                                                 const float* __restrict__ G,
                                                 const float* __restrict__ Bb,
                                                 unsigned short* __restrict__ Xo) {
  const int row = blockIdx.x;
  const float4* xr = (const float4*)(X + (size_t)row * DD);
  float s = 0.f, ss = 0.f;
  for (int i = threadIdx.x; i < DD / 4; i += 256) {
    float4 v = xr[i];
    s  += v.x + v.y + v.z + v.w;
    ss += v.x * v.x + v.y * v.y + v.z * v.z + v.w * v.w;
  }
#pragma unroll
  for (int o = 32; o > 0; o >>= 1) { s += __shfl_down(s, o, 64); ss += __shfl_down(ss, o, 64); }
  __shared__ float red[8];
  const int w = threadIdx.x >> 6;
  if ((threadIdx.x & 63) == 0) { red[w] = s; red[4 + w] = ss; }
  __syncthreads();
  if (threadIdx.x == 0) {
    float ts  = red[0] + red[1] + red[2] + red[3];
    float tss = red[4] + red[5] + red[6] + red[7];
    float mu  = ts * (1.f / DD);
    float var = tss * (1.f / DD) - mu * mu;
    red[0] = mu; red[1] = rsqrtf(var + 1e-5f);
  }
  __syncthreads();
  const float mu = red[0], rstd = red[1];
  const float4* gr = (const float4*)G;
  const float4* br = (const float4*)Bb;
  for (int i = threadIdx.x; i < DD / 4; i += 256) {
    float4 v = xr[i], g = gr[i], b = br[i];
    ushort4 o;
    o.x = f2bf((v.x - mu) * rstd * g.x + b.x);
    o.y = f2bf((v.y - mu) * rstd * g.y + b.y);
    o.z = f2bf((v.z - mu) * rstd * g.z + b.z);
    o.w = f2bf((v.w - mu) * rstd * g.w + b.w);
    *(ushort4*)&Xo[(size_t)row * DD + i * 4] = o;
  }
}

// ---------------- RoPE + head-layout ----------------
__global__ __launch_bounds__(256) void rope_kernel(const unsigned short* __restrict__ qkv,
                                                   unsigned short* __restrict__ Qp,
                                                   unsigned short* __restrict__ Kp,
                                                   unsigned short* __restrict__ Vt) {
  const int tok = blockIdx.x;
  const int b = tok / SS, s = tok % SS;
  __shared__ float cs[16], sn[16];
  if (threadIdx.x < 16) {
    float inv = powf(10000.f, -(float)threadIdx.x / 16.f);
    float ang = (float)s * inv;
    cs[threadIdx.x] = cosf(ang);
    sn[threadIdx.x] = sinf(ang);
  }
  __syncthreads();
  const unsigned short* row = qkv + (size_t)tok * (3 * DD);
  for (int idx = threadIdx.x; idx < 2 * HH * DPAD; idx += 256) {
    const int which = idx / (HH * DPAD);
    const int rrem  = idx % (HH * DPAD);
    const int h = rrem / DPAD, d = rrem % DPAD;
    float val = 0.f;
    if (d < DHH) {
      const unsigned short* base = row + which * DD + h * DHH;
      if (d < 16) {
        float x1 = bf2f(base[d]), x2 = bf2f(base[d + 16]);
        val = x1 * cs[d] - x2 * sn[d];
      } else if (d < 32) {
        int i2 = d - 16;
        float x1 = bf2f(base[i2]), x2 = bf2f(base[d]);
        val = x2 * cs[i2] + x1 * sn[i2];
      } else {
        val = bf2f(base[d]);
      }
    }
    unsigned short* outp = which ? Kp : Qp;
    outp[(((size_t)b * HH + h) * SS + s) * DPAD + d] = f2bf(val);
  }
  for (int idx = threadIdx.x; idx < DD; idx += 256) {
    const int h = idx / DHH, d = idx % DHH;
    Vt[(((size_t)b * HH + h) * DHH + d) * SS + s] = row[2 * DD + idx];
  }
}

// ---------------- flash attention (causal): 2 waves/block, 32 q-rows/wave, KVBLK=64 ----------------
__global__ __launch_bounds__(128) void attn_kernel(const unsigned short* __restrict__ Qp,
                                                   const unsigned short* __restrict__ Kp,
                                                   const unsigned short* __restrict__ Vt,
                                                   unsigned short* __restrict__ O) {
  const int bid = blockIdx.x;
  const int bh = bid & 63;
  const int p = 31 - (bid >> 6);        // heavy first (LPT)
  const int w = threadIdx.x >> 6;
  const int tile = p * 2 + w;
  const int lane = threadIdx.x & 63;
  const int lr = lane & 15, lg = lane >> 4;
  const int q0 = tile * 32;
  const unsigned short* Qh = Qp + (size_t)bh * SS * DPAD;
  const unsigned short* Kh = Kp + (size_t)bh * SS * DPAD;
  const unsigned short* Vh = Vt + (size_t)bh * DHH * SS;
  __shared__ __align__(16) char Plds[2][2][2048];

  bf16x8 qf[2][3];
#pragma unroll
  for (int g = 0; g < 2; ++g)
#pragma unroll
    for (int c = 0; c < 3; ++c)
      qf[g][c] = *(const bf16x8*)&Qh[(size_t)(q0 + g * 16 + lr) * DPAD + c * 32 + lg * 8];

  f32x4 oacc[2][5];
#pragma unroll
  for (int g = 0; g < 2; ++g)
#pragma unroll
    for (int d = 0; d < 5; ++d) oacc[g][d] = (f32x4){0.f, 0.f, 0.f, 0.f};
  float mrow[2][4], lrow[2][4];
#pragma unroll
  for (int g = 0; g < 2; ++g)
#pragma unroll
    for (int r = 0; r < 4; ++r) { mrow[g][r] = -1e30f; lrow[g][r] = 0.f; }

  const float scl = 0.11180339887498949f;
  const int nt = (q0 + 31) / 64 + 1;
  for (int t = 0; t < nt; ++t) {
    const int kv0 = t * 64;
    f32x4 s[2][4];
#pragma unroll
    for (int g = 0; g < 2; ++g)
#pragma unroll
      for (int j = 0; j < 4; ++j) s[g][j] = (f32x4){0.f, 0.f, 0.f, 0.f};
#pragma unroll
    for (int c = 0; c < 3; ++c) {
      bf16x8 kf[4];
#pragma unroll
      for (int j = 0; j < 4; ++j)
        kf[j] = *(const bf16x8*)&Kh[(size_t)(kv0 + j * 16 + lr) * DPAD + c * 32 + lg * 8];
#pragma unroll
      for (int g = 0; g < 2; ++g)
#pragma unroll
        for (int j = 0; j < 4; ++j)
          s[g][j] = __builtin_amdgcn_mfma_f32_16x16x32_bf16(qf[g][c], kf[j], s[g][j], 0, 0, 0);
    }
    float pv[2][4][4], mx[2][4];
    bool need = false;
#pragma unroll
    for (int g = 0; g < 2; ++g) {
#pragma unroll
      for (int r = 0; r < 4; ++r) {
        const int qr = q0 + g * 16 + lg * 4 + r;
        float m = -1e30f;
#pragma unroll
        for (int j = 0; j < 4; ++j) {
          float a = (kv0 + j * 16 + lr > qr) ? -1e30f : s[g][j][r] * scl;
          pv[g][j][r] = a;
          m = fmaxf(m, a);
        }
#pragma unroll
        for (int mk = 1; mk < 16; mk <<= 1) m = fmaxf(m, __shfl_xor(m, mk, 64));
        mx[g][r] = m;
        need = need || (m > mrow[g][r] + 8.f);
      }
    }
    if (__ballot(need)) {
#pragma unroll
      for (int g = 0; g < 2; ++g)
#pragma unroll
        for (int r = 0; r < 4; ++r) {
          float mnew = fmaxf(mrow[g][r], mx[g][r]);
          float resc = __expf(mrow[g][r] - mnew);
          lrow[g][r] *= resc;
#pragma unroll
          for (int d = 0; d < 5; ++d) oacc[g][d][r] *= resc;
          mrow[g][r] = mnew;
        }
    }
#pragma unroll
    for (int g = 0; g < 2; ++g) {
      char* Pb = Plds[w][g];
#pragma unroll
      for (int r = 0; r < 4; ++r) {
        const int row = lg * 4 + r;
        const int swz = (row & 7) << 4;
        float rs = 0.f;
#pragma unroll
        for (int j = 0; j < 4; ++j) {
          float pj = __expf(pv[g][j][r] - mrow[g][r]);
          rs += pj;
          *(unsigned short*)(Pb + row * 128 + (((j * 16 + lr) * 2) ^ swz)) = f2bf(pj);
        }
#pragma unroll
        for (int mk = 1; mk < 16; mk <<= 1) rs += __shfl_xor(rs, mk, 64);
        lrow[g][r] += rs;
      }
    }
    asm volatile("s_waitcnt lgkmcnt(0)" ::: "memory");
    const int rswz = (lr & 7) << 4;
    bf16x8 pa[2][2];
#pragma unroll
    for (int g = 0; g < 2; ++g) {
      pa[g][0] = *(const bf16x8*)(Plds[w][g] + lr * 128 + ((lg * 16) ^ rswz));
      pa[g][1] = *(const bf16x8*)(Plds[w][g] + lr * 128 + ((64 + lg * 16) ^ rswz));
    }
#pragma unroll
    for (int d = 0; d < 5; ++d) {
      bf16x8 v0 = *(const bf16x8*)&Vh[(size_t)(d * 16 + lr) * SS + kv0 + lg * 8];
      bf16x8 v1 = *(const bf16x8*)&Vh[(size_t)(d * 16 + lr) * SS + kv0 + 32 + lg * 8];
#pragma unroll
      for (int g = 0; g < 2; ++g) {
        oacc[g][d] = __builtin_amdgcn_mfma_f32_16x16x32_bf16(pa[g][0], v0, oacc[g][d], 0, 0, 0);
        oacc[g][d] = __builtin_amdgcn_mfma_f32_16x16x32_bf16(pa[g][1], v1, oacc[g][d], 0, 0, 0);
      }
    }
  }
  const int b = bh >> 5, h = bh & 31;
#pragma unroll
  for (int g = 0; g < 2; ++g)
#pragma unroll
    for (int r = 0; r < 4; ++r) {
      const int qr = q0 + g * 16 + lg * 4 + r;
      const float inv = 1.f / lrow[g][r];
#pragma unroll
      for (int d = 0; d < 5; ++d)
        O[(size_t)(b * SS + qr) * DD + h * DHH + d * 16 + lr] = f2bf(oacc[g][d][r] * inv);
    }
}

__device__ __forceinline__ float gelu_f(float x) {
  float x3 = x * x * x;
  return 0.5f * x * (1.f + tanhf(0.7978845608028654f * (x + 0.044715f * x3)));
}

// ---------------- 256x256 GEMM (verified 1216µs config): 8 waves, BK=64, 8-phase counted-vmcnt ----------------
template <int MODE>
__global__ __launch_bounds__(512, 2) void gemm256(const unsigned short* __restrict__ A,
                                                  const unsigned short* __restrict__ Bt,
                                                  const float* __restrict__ bias,
                                                  void* __restrict__ Cout,
                                                  const unsigned short* __restrict__ addb,
                                                  const float* __restrict__ addf,
                                                  int M, int N, int K, int nby) {
  __shared__ __align__(16) char lds[131072];

  const int bid = blockIdx.x;
  const int by = bid % nby, bx = bid / nby;   // column-major: A-panel L2 reuse
  const int m0 = by * 256, n0 = bx * 256;

  const int tid = threadIdx.x;
  const int w = tid >> 6, lane = tid & 63;
  const int lr = lane & 15, lg = lane >> 4;
  const int wm = w >> 2, wn = w & 3;

  const int srow = w * 16 + (lane >> 3);
  const int scol = ((lane & 7) ^ ((lane >> 3) & 7)) * 8;
  const unsigned short* pA = A  + (size_t)(m0 + srow) * K + scol;
  const unsigned short* pB = Bt + (size_t)(n0 + srow) * K + scol;
  const int wdst = w * 2048;

  const int rdA = wm * 16384 + lr * 128;
  const int rdB = 65536 + (wn >> 1) * 16384 + ((wn & 1) * 64 + lr) * 128;
  const int sl0 = ((lg) ^ (lr & 7)) << 4;
  const int sl1 = ((4 + lg) ^ (lr & 7)) << 4;

  f32x4 acc[8][4];
#pragma unroll
  for (int i = 0; i < 8; ++i)
#pragma unroll
    for (int j = 0; j < 4; ++j) acc[i][j] = (f32x4){0.f, 0.f, 0.f, 0.f};

  const int nt = K >> 6;

#define RA(BUF, m, kh) (*(const bf16x8*)(lds + (BUF) + rdA + (m) * 2048 + ((kh) ? sl1 : sl0)))
#define RB(BUF, n, kh) (*(const bf16x8*)(lds + (BUF) + rdB + (n) * 2048 + ((kh) ? sl1 : sl0)))
#define STGA(dt, h, DST)                                                       \
  { const unsigned short* s_ = pA + (size_t)(dt) * 64 + (size_t)(h) * 128 * K; \
    gl_lds16(s_,                 lds + (DST) + wdst);                          \
    gl_lds16(s_ + (size_t)8 * K, lds + (DST) + wdst + 1024); }
#define STGB(dt, h, DST)                                                       \
  { const unsigned short* s_ = pB + (size_t)(dt) * 64 + (size_t)(h) * 128 * K; \
    gl_lds16(s_,                 lds + 65536 + (DST) + wdst);                  \
    gl_lds16(s_ + (size_t)8 * K, lds + 65536 + (DST) + wdst + 1024); }
#define BARR __builtin_amdgcn_s_barrier()
#define MFMA8x2(AV, BV, MB, NB)                                              \
  __builtin_amdgcn_s_setprio(1);                                             \
  _Pragma("unroll") for (int kh_ = 0; kh_ < 2; ++kh_)                        \
  _Pragma("unroll") for (int m_ = 0; m_ < 4; ++m_)                           \
  _Pragma("unroll") for (int n_ = 0; n_ < 2; ++n_)                           \
    acc[(MB) + m_][(NB) + n_] = __builtin_amdgcn_mfma_f32_16x16x32_bf16(     \
        AV[m_][kh_], BV[n_][kh_], acc[(MB) + m_][(NB) + n_], 0, 0, 0);       \
  __builtin_amdgcn_s_setprio(0);

  STGA(0, 0, 0);
  STGA(0, 1, 16384);
  STGB(0, 0, 0);
  STGB(0, 1, 16384);
  STGA(1, 0, 32768);
  STGA(1, 1, 32768 + 16384);
  STGB(1, 0, 32768);
  asm volatile("s_waitcnt vmcnt(6)" ::: "memory");
  BARR;
  __builtin_amdgcn_sched_barrier(0);

  for (int t = 0; t < nt; t += 2) {
    const bool more = (t + 2 < nt);
    bf16x8 avL[4][2], avH[4][2], bvL[2][2], bvH[2][2];

#pragma unroll
    for (int m_ = 0; m_ < 4; ++m_) { avL[m_][0] = RA(0, m_, 0); avL[m_][1] = RA(0, m_, 1); }
#pragma unroll
    for (int n_ = 0; n_ < 2; ++n_) { bvL[n_][0] = RB(0, n_, 0); bvL[n_][1] = RB(0, n_, 1); }
    STGB(1, 1, 32768 + 16384);
    BARR;
    MFMA8x2(avL, bvL, 0, 0);
    BARR;
#pragma unroll
    for (int m_ = 0; m_ < 4; ++m_) { avH[m_][0] = RA(0, 4 + m_, 0); avH[m_][1] = RA(0, 4 + m_, 1); }
    BARR;
    MFMA8x2(avH, bvL, 4, 0);
    BARR;
#pragma unroll
    for (int n_ = 0; n_ < 2; ++n_) { bvH[n_][0] = RB(0, 2 + n_, 0); bvH[n_][1] = RB(0, 2 + n_, 1); }
    if (more) STGA(2, 0, 0);
    BARR;
    MFMA8x2(avH, bvH, 4, 2);
    BARR;
    if (more) STGA(2, 1, 16384);
    BARR;
    MFMA8x2(avL, bvH, 0, 2);
    if (more) { asm volatile("s_waitcnt vmcnt(4)" ::: "memory"); }
    else      { asm volatile("s_waitcnt vmcnt(0)" ::: "memory"); }
    BARR;
    __builtin_amdgcn_sched_barrier(0);

#pragma unroll
    for (int m_ = 0; m_ < 4; ++m_) { avL[m_][0] = RA(32768, m_, 0); avL[m_][1] = RA(32768, m_, 1); }
#pragma unroll
    for (int n_ = 0; n_ < 2; ++n_) { bvL[n_][0] = RB(32768, n_, 0); bvL[n_][1] = RB(32768, n_, 1); }
    if (more) STGB(2, 0, 0);
    BARR;
    MFMA8x2(avL, bvL, 0, 0);
    BARR;
#pragma unroll
    for (int m_ = 0; m_ < 4; ++m_) { avH[m_][0] = RA(32768, 4 + m_, 0); avH[m_][1] = RA(32768, 4 + m_, 1); }
    if (more) STGB(2, 1, 16384);
    BARR;
    MFMA8x2(avH, bvL, 4, 0);
    BARR;
#pragma unroll
    for (int n_ = 0; n_ < 2; ++n_) { bvH[n_][0] = RB(32768, 2 + n_, 0); bvH[n_][1] = RB(32768, 2 + n_, 1); }
    if (more) STGA(3, 0, 32768);
    BARR;
    MFMA8x2(avH, bvH, 4, 2);
    BARR;
    if (more) { STGA(3, 1, 32768 + 16384); STGB(3, 0, 32768); }
    BARR;
    MFMA8x2(avL, bvH, 0, 2);
    if (more) { asm volatile("s_waitcnt vmcnt(6)" ::: "memory"); }
    BARR;
    __builtin_amdgcn_sched_barrier(0);

    pA += 128; pB += 128;
  }
#undef RA
#undef RB
#undef STGA
#undef STGB
#undef BARR
#undef MFMA8x2

#pragma unroll
  for (int m = 0; m < 8; ++m) {
    const int rb = m0 + wm * 128 + m * 16 + lg * 4;
#pragma unroll
    for (int n = 0; n < 4; ++n) {
      const int col = n0 + wn * 64 + n * 16 + lr;
      const float bv = bias[col];
#pragma unroll
      for (int r = 0; r < 4; ++r) {
        const size_t idx = (size_t)(rb + r) * N + col;
        float v = acc[m][n][r] + bv;
        if (MODE == 2) v = gelu_f(v);
        if (MODE == 3) {
          ((float*)Cout)[idx] = v + bf2f(addb[idx]) + addf[idx];
        } else {
          ((unsigned short*)Cout)[idx] = f2bf(v);
        }
      }
    }
  }
}

extern "C" void kernel_launch(void* const* d_in, const int* in_sizes, int n_in,
                              void* d_out, int out_size, void* d_ws, size_t ws_size,
                              hipStream_t stream) {
  (void)in_sizes; (void)n_in; (void)out_size; (void)ws_size;
  const float* hidden = (const float*)d_in[1];
  const float* ln_g = (const float*)d_in[2];
  const float* ln_b = (const float*)d_in[3];
  const float* wqkv = (const float*)d_in[4];
  const float* bqkv = (const float*)d_in[5];
  const float* wout = (const float*)d_in[6];
  const float* bout = (const float*)d_in[7];
  const float* wfc1 = (const float*)d_in[8];
  const float* bfc1 = (const float*)d_in[9];
  const float* wfc2 = (const float*)d_in[10];
  const float* bfc2 = (const float*)d_in[11];
  float* out = (float*)d_out;

  char* ws = (char*)d_ws;
  size_t off = 0;
  auto alloc = [&](size_t bytes) -> void* {
    void* p = ws + off;
    off += (bytes + 255) & ~(size_t)255;
    return p;
  };
  unsigned short* wqkvT = (unsigned short*)alloc((size_t)3 * DD * DD * 2);
  unsigned short* woutT = (unsigned short*)alloc((size_t)DD * DD * 2);
  unsigned short* wfc1T = (unsigned short*)alloc((size_t)NII * DD * 2);
  unsigned short* wfc2T = (unsigned short*)alloc((size_t)DD * NII * 2);
  unsigned short* xln   = (unsigned short*)alloc((size_t)NTOK * DD * 2);
  unsigned short* regA  = (unsigned short*)alloc((size_t)NTOK * NII * 2);  // qkv, then h1
  unsigned short* Qp    = (unsigned short*)alloc((size_t)2 * HH * SS * DPAD * 2);  // then attn_proj
  unsigned short* Kp    = (unsigned short*)alloc((size_t)2 * HH * SS * DPAD * 2);
  unsigned short* Vt    = (unsigned short*)alloc((size_t)2 * HH * DHH * SS * 2);
  unsigned short* Obuf  = (unsigned short*)alloc((size_t)NTOK * DD * 2);
  unsigned short* qkvbuf   = regA;
  unsigned short* h1       = regA;
  unsigned short* attnproj = Qp;

  wt_transpose<<<dim3(3 * DD / 32, DD / 32), 256, 0, stream>>>(wqkv, wqkvT, DD, 3 * DD);
  wt_transpose<<<dim3(DD / 32, DD / 32), 256, 0, stream>>>(wout, woutT, DD, DD);
  wt_transpose<<<dim3(NII / 32, DD / 32), 256, 0, stream>>>(wfc1, wfc1T, DD, NII);
  wt_transpose<<<dim3(DD / 32, NII / 32), 256, 0, stream>>>(wfc2, wfc2T, NII, DD);
  ln_kernel<<<NTOK, 256, 0, stream>>>(hidden, ln_g, ln_b, xln);
  gemm256<0><<<dim3((3 * DD / 256) * (NTOK / 256)), 512, 0, stream>>>(
      xln, wqkvT, bqkv, qkvbuf, nullptr, nullptr, NTOK, 3 * DD, DD, NTOK / 256);
  rope_kernel<<<NTOK, 256, 0, stream>>>(qkvbuf, Qp, Kp, Vt);
  attn_kernel<<<dim3(2048), 128, 0, stream>>>(Qp, Kp, Vt, Obuf);
  gemm256<0><<<dim3((DD / 256) * (NTOK / 256)), 512, 0, stream>>>(
      Obuf, woutT, bout, attnproj, nullptr, nullptr, NTOK, DD, DD, NTOK / 256);
  gemm256<2><<<dim3((NII / 256) * (NTOK / 256)), 512, 0, stream>>>(
      xln, wfc1T, bfc1, h1, nullptr, nullptr, NTOK, NII, DD, NTOK / 256);
  gemm256<3><<<dim3((DD / 256) * (NTOK / 256)), 512, 0, stream>>>(
      h1, wfc2T, bfc2, out, attnproj, hidden, NTOK, DD, NII, NTOK / 256);
}

// Round 15
// 1220.778 us; speedup vs baseline: 1.0343x; 1.0023x over previous
//
#include <hip/hip_runtime.h>

#define SS   2048
#define DD   2560
#define HH   32
#define DHH  80
#define DPAD 96
#define NII  10240
#define NTOK 4096

typedef __attribute__((ext_vector_type(8))) __bf16 bf16x8;
typedef __attribute__((ext_vector_type(4))) float  f32x4;

__device__ __forceinline__ float bf2f(unsigned short h) {
  union { unsigned u; float f; } c; c.u = ((unsigned)h) << 16; return c.f;
}
__device__ __forceinline__ unsigned short f2bf(float f) {
  union { float f; unsigned u; } c; c.f = f;
  unsigned r = c.u + 0x7FFFu + ((c.u >> 16) & 1u);
  return (unsigned short)(r >> 16);
}

__device__ __forceinline__ void gl_lds16(const void* gptr, void* lptr) {
  __builtin_amdgcn_global_load_lds((__attribute__((address_space(1))) void*)gptr,
                                   (__attribute__((address_space(3))) void*)lptr,
                                   16, 0, 0);
}

// ---------------- weight transpose: W[K][N] fp32 -> Wt[N][K] bf16 (64x64, float4/ushort4) ----------------
__global__ __launch_bounds__(256) void wt_transpose(const float* __restrict__ W,
                                                    unsigned short* __restrict__ Wt,
                                                    int K, int N) {
  __shared__ float tile[64][65];
  const int t = threadIdx.x;
  const int n0 = blockIdx.x * 64, k0 = blockIdx.y * 64;
  const int rr = t >> 4, cc = (t & 15) * 4;
#pragma unroll
  for (int r = 0; r < 4; ++r) {
    const int row = r * 16 + rr;  // k-offset within tile
    float4 v = *(const float4*)&W[(size_t)(k0 + row) * N + n0 + cc];
    tile[row][cc + 0] = v.x;
    tile[row][cc + 1] = v.y;
    tile[row][cc + 2] = v.z;
    tile[row][cc + 3] = v.w;
  }
  __syncthreads();
#pragma unroll
  for (int r = 0; r < 4; ++r) {
    const int nrow = r * 16 + rr;  // n-offset within tile
    ushort4 o;
    o.x = f2bf(tile[cc + 0][nrow]);
    o.y = f2bf(tile[cc + 1][nrow]);
    o.z = f2bf(tile[cc + 2][nrow]);
    o.w = f2bf(tile[cc + 3][nrow]);
    *(ushort4*)&Wt[(size_t)(n0 + nrow) * K + k0 + cc] = o;
  }
}

// ---------------- LayerNorm: fp32 in -> bf16 out ----------------
__global__ __launch_bounds__(256) void ln_kernel(const float* __restrict__ X,
                                                 const float* __restrict__ G,
                                                 const float* __restrict__ Bb,
                                                 unsigned short* __restrict__ Xo) {
  const int row = blockIdx.x;
  const float4* xr = (const float4*)(X + (size_t)row * DD);
  float s = 0.f, ss = 0.f;
  for (int i = threadIdx.x; i < DD / 4; i += 256) {
    float4 v = xr[i];
    s  += v.x + v.y + v.z + v.w;
    ss += v.x * v.x + v.y * v.y + v.z * v.z + v.w * v.w;
  }
#pragma unroll
  for (int o = 32; o > 0; o >>= 1) { s += __shfl_down(s, o, 64); ss += __shfl_down(ss, o, 64); }
  __shared__ float red[8];
  const int w = threadIdx.x >> 6;
  if ((threadIdx.x & 63) == 0) { red[w] = s; red[4 + w] = ss; }
  __syncthreads();
  if (threadIdx.x == 0) {
    float ts  = red[0] + red[1] + red[2] + red[3];
    float tss = red[4] + red[5] + red[6] + red[7];
    float mu  = ts * (1.f / DD);
    float var = tss * (1.f / DD) - mu * mu;
    red[0] = mu; red[1] = rsqrtf(var + 1e-5f);
  }
  __syncthreads();
  const float mu = red[0], rstd = red[1];
  const float4* gr = (const float4*)G;
  const float4* br = (const float4*)Bb;
  for (int i = threadIdx.x; i < DD / 4; i += 256) {
    float4 v = xr[i], g = gr[i], b = br[i];
    ushort4 o;
    o.x = f2bf((v.x - mu) * rstd * g.x + b.x);
    o.y = f2bf((v.y - mu) * rstd * g.y + b.y);
    o.z = f2bf((v.z - mu) * rstd * g.z + b.z);
    o.w = f2bf((v.w - mu) * rstd * g.w + b.w);
    *(ushort4*)&Xo[(size_t)row * DD + i * 4] = o;
  }
}

// ---------------- RoPE + head-layout ----------------
__global__ __launch_bounds__(256) void rope_kernel(const unsigned short* __restrict__ qkv,
                                                   unsigned short* __restrict__ Qp,
                                                   unsigned short* __restrict__ Kp,
                                                   unsigned short* __restrict__ Vt) {
  const int tok = blockIdx.x;
  const int b = tok / SS, s = tok % SS;
  __shared__ float cs[16], sn[16];
  if (threadIdx.x < 16) {
    float inv = powf(10000.f, -(float)threadIdx.x / 16.f);
    float ang = (float)s * inv;
    cs[threadIdx.x] = cosf(ang);
    sn[threadIdx.x] = sinf(ang);
  }
  __syncthreads();
  const unsigned short* row = qkv + (size_t)tok * (3 * DD);
  for (int idx = threadIdx.x; idx < 2 * HH * DPAD; idx += 256) {
    const int which = idx / (HH * DPAD);
    const int rrem  = idx % (HH * DPAD);
    const int h = rrem / DPAD, d = rrem % DPAD;
    float val = 0.f;
    if (d < DHH) {
      const unsigned short* base = row + which * DD + h * DHH;
      if (d < 16) {
        float x1 = bf2f(base[d]), x2 = bf2f(base[d + 16]);
        val = x1 * cs[d] - x2 * sn[d];
      } else if (d < 32) {
        int i2 = d - 16;
        float x1 = bf2f(base[i2]), x2 = bf2f(base[d]);
        val = x2 * cs[i2] + x1 * sn[i2];
      } else {
        val = bf2f(base[d]);
      }
    }
    unsigned short* outp = which ? Kp : Qp;
    outp[(((size_t)b * HH + h) * SS + s) * DPAD + d] = f2bf(val);
  }
  for (int idx = threadIdx.x; idx < DD; idx += 256) {
    const int h = idx / DHH, d = idx % DHH;
    Vt[(((size_t)b * HH + h) * DHH + d) * SS + s] = row[2 * DD + idx];
  }
}

// ---------------- flash attention (causal): 2 waves/block, 32 q-rows/wave, KVBLK=64 ----------------
__global__ __launch_bounds__(128) void attn_kernel(const unsigned short* __restrict__ Qp,
                                                   const unsigned short* __restrict__ Kp,
                                                   const unsigned short* __restrict__ Vt,
                                                   unsigned short* __restrict__ O) {
  const int bid = blockIdx.x;
  const int bh = bid & 63;
  const int p = 31 - (bid >> 6);        // heavy first (LPT)
  const int w = threadIdx.x >> 6;
  const int tile = p * 2 + w;
  const int lane = threadIdx.x & 63;
  const int lr = lane & 15, lg = lane >> 4;
  const int q0 = tile * 32;
  const unsigned short* Qh = Qp + (size_t)bh * SS * DPAD;
  const unsigned short* Kh = Kp + (size_t)bh * SS * DPAD;
  const unsigned short* Vh = Vt + (size_t)bh * DHH * SS;
  __shared__ __align__(16) char Plds[2][2][2048];

  bf16x8 qf[2][3];
#pragma unroll
  for (int g = 0; g < 2; ++g)
#pragma unroll
    for (int c = 0; c < 3; ++c)
      qf[g][c] = *(const bf16x8*)&Qh[(size_t)(q0 + g * 16 + lr) * DPAD + c * 32 + lg * 8];

  f32x4 oacc[2][5];
#pragma unroll
  for (int g = 0; g < 2; ++g)
#pragma unroll
    for (int d = 0; d < 5; ++d) oacc[g][d] = (f32x4){0.f, 0.f, 0.f, 0.f};
  float mrow[2][4], lrow[2][4];
#pragma unroll
  for (int g = 0; g < 2; ++g)
#pragma unroll
    for (int r = 0; r < 4; ++r) { mrow[g][r] = -1e30f; lrow[g][r] = 0.f; }

  const float scl = 0.11180339887498949f;
  const int nt = (q0 + 31) / 64 + 1;
  for (int t = 0; t < nt; ++t) {
    const int kv0 = t * 64;
    f32x4 s[2][4];
#pragma unroll
    for (int g = 0; g < 2; ++g)
#pragma unroll
      for (int j = 0; j < 4; ++j) s[g][j] = (f32x4){0.f, 0.f, 0.f, 0.f};
#pragma unroll
    for (int c = 0; c < 3; ++c) {
      bf16x8 kf[4];
#pragma unroll
      for (int j = 0; j < 4; ++j)
        kf[j] = *(const bf16x8*)&Kh[(size_t)(kv0 + j * 16 + lr) * DPAD + c * 32 + lg * 8];
#pragma unroll
      for (int g = 0; g < 2; ++g)
#pragma unroll
        for (int j = 0; j < 4; ++j)
          s[g][j] = __builtin_amdgcn_mfma_f32_16x16x32_bf16(qf[g][c], kf[j], s[g][j], 0, 0, 0);
    }
    float pv[2][4][4], mx[2][4];
    bool need = false;
#pragma unroll
    for (int g = 0; g < 2; ++g) {
#pragma unroll
      for (int r = 0; r < 4; ++r) {
        const int qr = q0 + g * 16 + lg * 4 + r;
        float m = -1e30f;
#pragma unroll
        for (int j = 0; j < 4; ++j) {
          float a = (kv0 + j * 16 + lr > qr) ? -1e30f : s[g][j][r] * scl;
          pv[g][j][r] = a;
          m = fmaxf(m, a);
        }
#pragma unroll
        for (int mk = 1; mk < 16; mk <<= 1) m = fmaxf(m, __shfl_xor(m, mk, 64));
        mx[g][r] = m;
        need = need || (m > mrow[g][r] + 8.f);
      }
    }
    if (__ballot(need)) {
#pragma unroll
      for (int g = 0; g < 2; ++g)
#pragma unroll
        for (int r = 0; r < 4; ++r) {
          float mnew = fmaxf(mrow[g][r], mx[g][r]);
          float resc = __expf(mrow[g][r] - mnew);
          lrow[g][r] *= resc;
#pragma unroll
          for (int d = 0; d < 5; ++d) oacc[g][d][r] *= resc;
          mrow[g][r] = mnew;
        }
    }
#pragma unroll
    for (int g = 0; g < 2; ++g) {
      char* Pb = Plds[w][g];
#pragma unroll
      for (int r = 0; r < 4; ++r) {
        const int row = lg * 4 + r;
        const int swz = (row & 7) << 4;
        float rs = 0.f;
#pragma unroll
        for (int j = 0; j < 4; ++j) {
          float pj = __expf(pv[g][j][r] - mrow[g][r]);
          rs += pj;
          *(unsigned short*)(Pb + row * 128 + (((j * 16 + lr) * 2) ^ swz)) = f2bf(pj);
        }
#pragma unroll
        for (int mk = 1; mk < 16; mk <<= 1) rs += __shfl_xor(rs, mk, 64);
        lrow[g][r] += rs;
      }
    }
    asm volatile("s_waitcnt lgkmcnt(0)" ::: "memory");
    const int rswz = (lr & 7) << 4;
    bf16x8 pa[2][2];
#pragma unroll
    for (int g = 0; g < 2; ++g) {
      pa[g][0] = *(const bf16x8*)(Plds[w][g] + lr * 128 + ((lg * 16) ^ rswz));
      pa[g][1] = *(const bf16x8*)(Plds[w][g] + lr * 128 + ((64 + lg * 16) ^ rswz));
    }
#pragma unroll
    for (int d = 0; d < 5; ++d) {
      bf16x8 v0 = *(const bf16x8*)&Vh[(size_t)(d * 16 + lr) * SS + kv0 + lg * 8];
      bf16x8 v1 = *(const bf16x8*)&Vh[(size_t)(d * 16 + lr) * SS + kv0 + 32 + lg * 8];
#pragma unroll
      for (int g = 0; g < 2; ++g) {
        oacc[g][d] = __builtin_amdgcn_mfma_f32_16x16x32_bf16(pa[g][0], v0, oacc[g][d], 0, 0, 0);
        oacc[g][d] = __builtin_amdgcn_mfma_f32_16x16x32_bf16(pa[g][1], v1, oacc[g][d], 0, 0, 0);
      }
    }
  }
  const int b = bh >> 5, h = bh & 31;
#pragma unroll
  for (int g = 0; g < 2; ++g)
#pragma unroll
    for (int r = 0; r < 4; ++r) {
      const int qr = q0 + g * 16 + lg * 4 + r;
      const float inv = 1.f / lrow[g][r];
#pragma unroll
      for (int d = 0; d < 5; ++d)
        O[(size_t)(b * SS + qr) * DD + h * DHH + d * 16 + lr] = f2bf(oacc[g][d][r] * inv);
    }
}

__device__ __forceinline__ float gelu_f(float x) {
  float x3 = x * x * x;
  return 0.5f * x * (1.f + tanhf(0.7978845608028654f * (x + 0.044715f * x3)));
}

// ---------------- 256x256 GEMM (verified 1216µs config): 8 waves, BK=64, 8-phase counted-vmcnt ----------------
template <int MODE>
__global__ __launch_bounds__(512, 2) void gemm256(const unsigned short* __restrict__ A,
                                                  const unsigned short* __restrict__ Bt,
                                                  const float* __restrict__ bias,
                                                  void* __restrict__ Cout,
                                                  const unsigned short* __restrict__ addb,
                                                  const float* __restrict__ addf,
                                                  int M, int N, int K, int nby) {
  __shared__ __align__(16) char lds[131072];

  const int bid = blockIdx.x;
  const int by = bid % nby, bx = bid / nby;   // column-major: A-panel L2 reuse
  const int m0 = by * 256, n0 = bx * 256;

  const int tid = threadIdx.x;
  const int w = tid >> 6, lane = tid & 63;
  const int lr = lane & 15, lg = lane >> 4;
  const int wm = w >> 2, wn = w & 3;

  const int srow = w * 16 + (lane >> 3);
  const int scol = ((lane & 7) ^ ((lane >> 3) & 7)) * 8;
  const unsigned short* pA = A  + (size_t)(m0 + srow) * K + scol;
  const unsigned short* pB = Bt + (size_t)(n0 + srow) * K + scol;
  const int wdst = w * 2048;

  const int rdA = wm * 16384 + lr * 128;
  const int rdB = 65536 + (wn >> 1) * 16384 + ((wn & 1) * 64 + lr) * 128;
  const int sl0 = ((lg) ^ (lr & 7)) << 4;
  const int sl1 = ((4 + lg) ^ (lr & 7)) << 4;

  f32x4 acc[8][4];
#pragma unroll
  for (int i = 0; i < 8; ++i)
#pragma unroll
    for (int j = 0; j < 4; ++j) acc[i][j] = (f32x4){0.f, 0.f, 0.f, 0.f};

  const int nt = K >> 6;

#define RA(BUF, m, kh) (*(const bf16x8*)(lds + (BUF) + rdA + (m) * 2048 + ((kh) ? sl1 : sl0)))
#define RB(BUF, n, kh) (*(const bf16x8*)(lds + (BUF) + rdB + (n) * 2048 + ((kh) ? sl1 : sl0)))
#define STGA(dt, h, DST)                                                       \
  { const unsigned short* s_ = pA + (size_t)(dt) * 64 + (size_t)(h) * 128 * K; \
    gl_lds16(s_,                 lds + (DST) + wdst);                          \
    gl_lds16(s_ + (size_t)8 * K, lds + (DST) + wdst + 1024); }
#define STGB(dt, h, DST)                                                       \
  { const unsigned short* s_ = pB + (size_t)(dt) * 64 + (size_t)(h) * 128 * K; \
    gl_lds16(s_,                 lds + 65536 + (DST) + wdst);                  \
    gl_lds16(s_ + (size_t)8 * K, lds + 65536 + (DST) + wdst + 1024); }
#define BARR __builtin_amdgcn_s_barrier()
#define MFMA8x2(AV, BV, MB, NB)                                              \
  __builtin_amdgcn_s_setprio(1);                                             \
  _Pragma("unroll") for (int kh_ = 0; kh_ < 2; ++kh_)                        \
  _Pragma("unroll") for (int m_ = 0; m_ < 4; ++m_)                           \
  _Pragma("unroll") for (int n_ = 0; n_ < 2; ++n_)                           \
    acc[(MB) + m_][(NB) + n_] = __builtin_amdgcn_mfma_f32_16x16x32_bf16(     \
        AV[m_][kh_], BV[n_][kh_], acc[(MB) + m_][(NB) + n_], 0, 0, 0);       \
  __builtin_amdgcn_s_setprio(0);

  STGA(0, 0, 0);
  STGA(0, 1, 16384);
  STGB(0, 0, 0);
  STGB(0, 1, 16384);
  STGA(1, 0, 32768);
  STGA(1, 1, 32768 + 16384);
  STGB(1, 0, 32768);
  asm volatile("s_waitcnt vmcnt(6)" ::: "memory");
  BARR;
  __builtin_amdgcn_sched_barrier(0);

  for (int t = 0; t < nt; t += 2) {
    const bool more = (t + 2 < nt);
    bf16x8 avL[4][2], avH[4][2], bvL[2][2], bvH[2][2];

#pragma unroll
    for (int m_ = 0; m_ < 4; ++m_) { avL[m_][0] = RA(0, m_, 0); avL[m_][1] = RA(0, m_, 1); }
#pragma unroll
    for (int n_ = 0; n_ < 2; ++n_) { bvL[n_][0] = RB(0, n_, 0); bvL[n_][1] = RB(0, n_, 1); }
    STGB(1, 1, 32768 + 16384);
    BARR;
    MFMA8x2(avL, bvL, 0, 0);
    BARR;
#pragma unroll
    for (int m_ = 0; m_ < 4; ++m_) { avH[m_][0] = RA(0, 4 + m_, 0); avH[m_][1] = RA(0, 4 + m_, 1); }
    BARR;
    MFMA8x2(avH, bvL, 4, 0);
    BARR;
#pragma unroll
    for (int n_ = 0; n_ < 2; ++n_) { bvH[n_][0] = RB(0, 2 + n_, 0); bvH[n_][1] = RB(0, 2 + n_, 1); }
    if (more) STGA(2, 0, 0);
    BARR;
    MFMA8x2(avH, bvH, 4, 2);
    BARR;
    if (more) STGA(2, 1, 16384);
    BARR;
    MFMA8x2(avL, bvH, 0, 2);
    if (more) { asm volatile("s_waitcnt vmcnt(4)" ::: "memory"); }
    else      { asm volatile("s_waitcnt vmcnt(0)" ::: "memory"); }
    BARR;
    __builtin_amdgcn_sched_barrier(0);

#pragma unroll
    for (int m_ = 0; m_ < 4; ++m_) { avL[m_][0] = RA(32768, m_, 0); avL[m_][1] = RA(32768, m_, 1); }
#pragma unroll
    for (int n_ = 0; n_ < 2; ++n_) { bvL[n_][0] = RB(32768, n_, 0); bvL[n_][1] = RB(32768, n_, 1); }
    if (more) STGB(2, 0, 0);
    BARR;
    MFMA8x2(avL, bvL, 0, 0);
    BARR;
#pragma unroll
    for (int m_ = 0; m_ < 4; ++m_) { avH[m_][0] = RA(32768, 4 + m_, 0); avH[m_][1] = RA(32768, 4 + m_, 1); }
    if (more) STGB(2, 1, 16384);
    BARR;
    MFMA8x2(avH, bvL, 4, 0);
    BARR;
#pragma unroll
    for (int n_ = 0; n_ < 2; ++n_) { bvH[n_][0] = RB(32768, 2 + n_, 0); bvH[n_][1] = RB(32768, 2 + n_, 1); }
    if (more) STGA(3, 0, 32768);
    BARR;
    MFMA8x2(avH, bvH, 4, 2);
    BARR;
    if (more) { STGA(3, 1, 32768 + 16384); STGB(3, 0, 32768); }
    BARR;
    MFMA8x2(avL, bvH, 0, 2);
    if (more) { asm volatile("s_waitcnt vmcnt(6)" ::: "memory"); }
    BARR;
    __builtin_amdgcn_sched_barrier(0);

    pA += 128; pB += 128;
  }
#undef RA
#undef RB
#undef STGA
#undef STGB
#undef BARR
#undef MFMA8x2

#pragma unroll
  for (int m = 0; m < 8; ++m) {
    const int rb = m0 + wm * 128 + m * 16 + lg * 4;
#pragma unroll
    for (int n = 0; n < 4; ++n) {
      const int col = n0 + wn * 64 + n * 16 + lr;
      const float bv = bias[col];
#pragma unroll
      for (int r = 0; r < 4; ++r) {
        const size_t idx = (size_t)(rb + r) * N + col;
        float v = acc[m][n][r] + bv;
        if (MODE == 2) v = gelu_f(v);
        if (MODE == 3) {
          ((float*)Cout)[idx] = v + bf2f(addb[idx]) + addf[idx];
        } else {
          ((unsigned short*)Cout)[idx] = f2bf(v);
        }
      }
    }
  }
}

extern "C" void kernel_launch(void* const* d_in, const int* in_sizes, int n_in,
                              void* d_out, int out_size, void* d_ws, size_t ws_size,
                              hipStream_t stream) {
  (void)in_sizes; (void)n_in; (void)out_size; (void)ws_size;
  const float* hidden = (const float*)d_in[1];
  const float* ln_g = (const float*)d_in[2];
  const float* ln_b = (const float*)d_in[3];
  const float* wqkv = (const float*)d_in[4];
  const float* bqkv = (const float*)d_in[5];
  const float* wout = (const float*)d_in[6];
  const float* bout = (const float*)d_in[7];
  const float* wfc1 = (const float*)d_in[8];
  const float* bfc1 = (const float*)d_in[9];
  const float* wfc2 = (const float*)d_in[10];
  const float* bfc2 = (const float*)d_in[11];
  float* out = (float*)d_out;

  char* ws = (char*)d_ws;
  size_t off = 0;
  auto alloc = [&](size_t bytes) -> void* {
    void* p = ws + off;
    off += (bytes + 255) & ~(size_t)255;
    return p;
  };
  unsigned short* wqkvT = (unsigned short*)alloc((size_t)3 * DD * DD * 2);
  unsigned short* woutT = (unsigned short*)alloc((size_t)DD * DD * 2);
  unsigned short* wfc1T = (unsigned short*)alloc((size_t)NII * DD * 2);
  unsigned short* wfc2T = (unsigned short*)alloc((size_t)DD * NII * 2);
  unsigned short* xln   = (unsigned short*)alloc((size_t)NTOK * DD * 2);
  unsigned short* regA  = (unsigned short*)alloc((size_t)NTOK * NII * 2);  // qkv, then h1
  unsigned short* Qp    = (unsigned short*)alloc((size_t)2 * HH * SS * DPAD * 2);  // then attn_proj
  unsigned short* Kp    = (unsigned short*)alloc((size_t)2 * HH * SS * DPAD * 2);
  unsigned short* Vt    = (unsigned short*)alloc((size_t)2 * HH * DHH * SS * 2);
  unsigned short* Obuf  = (unsigned short*)alloc((size_t)NTOK * DD * 2);
  unsigned short* qkvbuf   = regA;
  unsigned short* h1       = regA;
  unsigned short* attnproj = Qp;

  wt_transpose<<<dim3(3 * DD / 64, DD / 64), 256, 0, stream>>>(wqkv, wqkvT, DD, 3 * DD);
  wt_transpose<<<dim3(DD / 64, DD / 64), 256, 0, stream>>>(wout, woutT, DD, DD);
  wt_transpose<<<dim3(NII / 64, DD / 64), 256, 0, stream>>>(wfc1, wfc1T, DD, NII);
  wt_transpose<<<dim3(DD / 64, NII / 64), 256, 0, stream>>>(wfc2, wfc2T, NII, DD);
  ln_kernel<<<NTOK, 256, 0, stream>>>(hidden, ln_g, ln_b, xln);
  gemm256<0><<<dim3((3 * DD / 256) * (NTOK / 256)), 512, 0, stream>>>(
      xln, wqkvT, bqkv, qkvbuf, nullptr, nullptr, NTOK, 3 * DD, DD, NTOK / 256);
  rope_kernel<<<NTOK, 256, 0, stream>>>(qkvbuf, Qp, Kp, Vt);
  attn_kernel<<<dim3(2048), 128, 0, stream>>>(Qp, Kp, Vt, Obuf);
  gemm256<0><<<dim3((DD / 256) * (NTOK / 256)), 512, 0, stream>>>(
      Obuf, woutT, bout, attnproj, nullptr, nullptr, NTOK, DD, DD, NTOK / 256);
  gemm256<2><<<dim3((NII / 256) * (NTOK / 256)), 512, 0, stream>>>(
      xln, wfc1T, bfc1, h1, nullptr, nullptr, NTOK, NII, DD, NTOK / 256);
  gemm256<3><<<dim3((DD / 256) * (NTOK / 256)), 512, 0, stream>>>(
      h1, wfc2T, bfc2, out, attnproj, hidden, NTOK, DD, NII, NTOK / 256);
}

// Round 16
// 1214.375 us; speedup vs baseline: 1.0398x; 1.0053x over previous
//
#include <hip/hip_runtime.h>

#define SS   2048
#define DD   2560
#define HH   32
#define DHH  80
#define DPAD 96
#define NII  10240
#define NTOK 4096

typedef __attribute__((ext_vector_type(8))) __bf16 bf16x8;
typedef __attribute__((ext_vector_type(4))) float  f32x4;

__device__ __forceinline__ float bf2f(unsigned short h) {
  union { unsigned u; float f; } c; c.u = ((unsigned)h) << 16; return c.f;
}
__device__ __forceinline__ unsigned short f2bf(float f) {
  union { float f; unsigned u; } c; c.f = f;
  unsigned r = c.u + 0x7FFFu + ((c.u >> 16) & 1u);
  return (unsigned short)(r >> 16);
}

__device__ __forceinline__ void gl_lds16(const void* gptr, void* lptr) {
  __builtin_amdgcn_global_load_lds((__attribute__((address_space(1))) void*)gptr,
                                   (__attribute__((address_space(3))) void*)lptr,
                                   16, 0, 0);
}

// ---------------- fused weight transpose: all 4 weights, W[K][N] fp32 -> Wt[N][K] bf16 ----------------
// grid partition (64x64 tiles): wqkv 120x40=4800 | wout 40x40=1600 | wfc1 160x40=6400 | wfc2 40x160=6400
__global__ __launch_bounds__(256) void wt_transpose_all(const float* __restrict__ Wq,
                                                        const float* __restrict__ Wo,
                                                        const float* __restrict__ W1,
                                                        const float* __restrict__ W2,
                                                        unsigned short* __restrict__ Tq,
                                                        unsigned short* __restrict__ To,
                                                        unsigned short* __restrict__ T1,
                                                        unsigned short* __restrict__ T2) {
  int bid = blockIdx.x;
  const float* W; unsigned short* Wt; int K, N, bx;
  if (bid < 4800)        { W = Wq; Wt = Tq; K = DD;  N = 3 * DD; bx = 120; }
  else if (bid < 6400)   { bid -= 4800; W = Wo; Wt = To; K = DD;  N = DD;  bx = 40; }
  else if (bid < 12800)  { bid -= 6400; W = W1; Wt = T1; K = DD;  N = NII; bx = 160; }
  else                   { bid -= 12800; W = W2; Wt = T2; K = NII; N = DD; bx = 40; }
  const int n0 = (bid % bx) * 64, k0 = (bid / bx) * 64;

  __shared__ float tile[64][65];
  const int t = threadIdx.x;
  const int rr = t >> 4, cc = (t & 15) * 4;
#pragma unroll
  for (int r = 0; r < 4; ++r) {
    const int row = r * 16 + rr;
    float4 v = *(const float4*)&W[(size_t)(k0 + row) * N + n0 + cc];
    tile[row][cc + 0] = v.x;
    tile[row][cc + 1] = v.y;
    tile[row][cc + 2] = v.z;
    tile[row][cc + 3] = v.w;
  }
  __syncthreads();
#pragma unroll
  for (int r = 0; r < 4; ++r) {
    const int nrow = r * 16 + rr;
    ushort4 o;
    o.x = f2bf(tile[cc + 0][nrow]);
    o.y = f2bf(tile[cc + 1][nrow]);
    o.z = f2bf(tile[cc + 2][nrow]);
    o.w = f2bf(tile[cc + 3][nrow]);
    *(ushort4*)&Wt[(size_t)(n0 + nrow) * K + k0 + cc] = o;
  }
}

// ---------------- LayerNorm: fp32 in -> bf16 out ----------------
__global__ __launch_bounds__(256) void ln_kernel(const float* __restrict__ X,
                                                 const float* __restrict__ G,
                                                 const float* __restrict__ Bb,
                                                 unsigned short* __restrict__ Xo) {
  const int row = blockIdx.x;
  const float4* xr = (const float4*)(X + (size_t)row * DD);
  float s = 0.f, ss = 0.f;
  for (int i = threadIdx.x; i < DD / 4; i += 256) {
    float4 v = xr[i];
    s  += v.x + v.y + v.z + v.w;
    ss += v.x * v.x + v.y * v.y + v.z * v.z + v.w * v.w;
  }
#pragma unroll
  for (int o = 32; o > 0; o >>= 1) { s += __shfl_down(s, o, 64); ss += __shfl_down(ss, o, 64); }
  __shared__ float red[8];
  const int w = threadIdx.x >> 6;
  if ((threadIdx.x & 63) == 0) { red[w] = s; red[4 + w] = ss; }
  __syncthreads();
  if (threadIdx.x == 0) {
    float ts  = red[0] + red[1] + red[2] + red[3];
    float tss = red[4] + red[5] + red[6] + red[7];
    float mu  = ts * (1.f / DD);
    float var = tss * (1.f / DD) - mu * mu;
    red[0] = mu; red[1] = rsqrtf(var + 1e-5f);
  }
  __syncthreads();
  const float mu = red[0], rstd = red[1];
  const float4* gr = (const float4*)G;
  const float4* br = (const float4*)Bb;
  for (int i = threadIdx.x; i < DD / 4; i += 256) {
    float4 v = xr[i], g = gr[i], b = br[i];
    ushort4 o;
    o.x = f2bf((v.x - mu) * rstd * g.x + b.x);
    o.y = f2bf((v.y - mu) * rstd * g.y + b.y);
    o.z = f2bf((v.z - mu) * rstd * g.z + b.z);
    o.w = f2bf((v.w - mu) * rstd * g.w + b.w);
    *(ushort4*)&Xo[(size_t)row * DD + i * 4] = o;
  }
}

// ---------------- RoPE + head-layout ----------------
__global__ __launch_bounds__(256) void rope_kernel(const unsigned short* __restrict__ qkv,
                                                   unsigned short* __restrict__ Qp,
                                                   unsigned short* __restrict__ Kp,
                                                   unsigned short* __restrict__ Vt) {
  const int tok = blockIdx.x;
  const int b = tok / SS, s = tok % SS;
  __shared__ float cs[16], sn[16];
  if (threadIdx.x < 16) {
    float inv = powf(10000.f, -(float)threadIdx.x / 16.f);
    float ang = (float)s * inv;
    cs[threadIdx.x] = cosf(ang);
    sn[threadIdx.x] = sinf(ang);
  }
  __syncthreads();
  const unsigned short* row = qkv + (size_t)tok * (3 * DD);
  for (int idx = threadIdx.x; idx < 2 * HH * DPAD; idx += 256) {
    const int which = idx / (HH * DPAD);
    const int rrem  = idx % (HH * DPAD);
    const int h = rrem / DPAD, d = rrem % DPAD;
    float val = 0.f;
    if (d < DHH) {
      const unsigned short* base = row + which * DD + h * DHH;
      if (d < 16) {
        float x1 = bf2f(base[d]), x2 = bf2f(base[d + 16]);
        val = x1 * cs[d] - x2 * sn[d];
      } else if (d < 32) {
        int i2 = d - 16;
        float x1 = bf2f(base[i2]), x2 = bf2f(base[d]);
        val = x2 * cs[i2] + x1 * sn[i2];
      } else {
        val = bf2f(base[d]);
      }
    }
    unsigned short* outp = which ? Kp : Qp;
    outp[(((size_t)b * HH + h) * SS + s) * DPAD + d] = f2bf(val);
  }
  for (int idx = threadIdx.x; idx < DD; idx += 256) {
    const int h = idx / DHH, d = idx % DHH;
    Vt[(((size_t)b * HH + h) * DHH + d) * SS + s] = row[2 * DD + idx];
  }
}

// ---------------- flash attention (causal): 2 waves/block, 32 q-rows/wave, KVBLK=64 ----------------
__global__ __launch_bounds__(128) void attn_kernel(const unsigned short* __restrict__ Qp,
                                                   const unsigned short* __restrict__ Kp,
                                                   const unsigned short* __restrict__ Vt,
                                                   unsigned short* __restrict__ O) {
  const int bid = blockIdx.x;
  const int bh = bid & 63;
  const int p = 31 - (bid >> 6);        // heavy first (LPT)
  const int w = threadIdx.x >> 6;
  const int tile = p * 2 + w;
  const int lane = threadIdx.x & 63;
  const int lr = lane & 15, lg = lane >> 4;
  const int q0 = tile * 32;
  const unsigned short* Qh = Qp + (size_t)bh * SS * DPAD;
  const unsigned short* Kh = Kp + (size_t)bh * SS * DPAD;
  const unsigned short* Vh = Vt + (size_t)bh * DHH * SS;
  __shared__ __align__(16) char Plds[2][2][2048];

  bf16x8 qf[2][3];
#pragma unroll
  for (int g = 0; g < 2; ++g)
#pragma unroll
    for (int c = 0; c < 3; ++c)
      qf[g][c] = *(const bf16x8*)&Qh[(size_t)(q0 + g * 16 + lr) * DPAD + c * 32 + lg * 8];

  f32x4 oacc[2][5];
#pragma unroll
  for (int g = 0; g < 2; ++g)
#pragma unroll
    for (int d = 0; d < 5; ++d) oacc[g][d] = (f32x4){0.f, 0.f, 0.f, 0.f};
  float mrow[2][4], lrow[2][4];
#pragma unroll
  for (int g = 0; g < 2; ++g)
#pragma unroll
    for (int r = 0; r < 4; ++r) { mrow[g][r] = -1e30f; lrow[g][r] = 0.f; }

  const float scl = 0.11180339887498949f;
  const int nt = (q0 + 31) / 64 + 1;
  for (int t = 0; t < nt; ++t) {
    const int kv0 = t * 64;
    f32x4 s[2][4];
#pragma unroll
    for (int g = 0; g < 2; ++g)
#pragma unroll
      for (int j = 0; j < 4; ++j) s[g][j] = (f32x4){0.f, 0.f, 0.f, 0.f};
#pragma unroll
    for (int c = 0; c < 3; ++c) {
      bf16x8 kf[4];
#pragma unroll
      for (int j = 0; j < 4; ++j)
        kf[j] = *(const bf16x8*)&Kh[(size_t)(kv0 + j * 16 + lr) * DPAD + c * 32 + lg * 8];
#pragma unroll
      for (int g = 0; g < 2; ++g)
#pragma unroll
        for (int j = 0; j < 4; ++j)
          s[g][j] = __builtin_amdgcn_mfma_f32_16x16x32_bf16(qf[g][c], kf[j], s[g][j], 0, 0, 0);
    }
    float pv[2][4][4], mx[2][4];
    bool need = false;
#pragma unroll
    for (int g = 0; g < 2; ++g) {
#pragma unroll
      for (int r = 0; r < 4; ++r) {
        const int qr = q0 + g * 16 + lg * 4 + r;
        float m = -1e30f;
#pragma unroll
        for (int j = 0; j < 4; ++j) {
          float a = (kv0 + j * 16 + lr > qr) ? -1e30f : s[g][j][r] * scl;
          pv[g][j][r] = a;
          m = fmaxf(m, a);
        }
#pragma unroll
        for (int mk = 1; mk < 16; mk <<= 1) m = fmaxf(m, __shfl_xor(m, mk, 64));
        mx[g][r] = m;
        need = need || (m > mrow[g][r] + 8.f);
      }
    }
    if (__ballot(need)) {
#pragma unroll
      for (int g = 0; g < 2; ++g)
#pragma unroll
        for (int r = 0; r < 4; ++r) {
          float mnew = fmaxf(mrow[g][r], mx[g][r]);
          float resc = __expf(mrow[g][r] - mnew);
          lrow[g][r] *= resc;
#pragma unroll
          for (int d = 0; d < 5; ++d) oacc[g][d][r] *= resc;
          mrow[g][r] = mnew;
        }
    }
#pragma unroll
    for (int g = 0; g < 2; ++g) {
      char* Pb = Plds[w][g];
#pragma unroll
      for (int r = 0; r < 4; ++r) {
        const int row = lg * 4 + r;
        const int swz = (row & 7) << 4;
        float rs = 0.f;
#pragma unroll
        for (int j = 0; j < 4; ++j) {
          float pj = __expf(pv[g][j][r] - mrow[g][r]);
          rs += pj;
          *(unsigned short*)(Pb + row * 128 + (((j * 16 + lr) * 2) ^ swz)) = f2bf(pj);
        }
#pragma unroll
        for (int mk = 1; mk < 16; mk <<= 1) rs += __shfl_xor(rs, mk, 64);
        lrow[g][r] += rs;
      }
    }
    asm volatile("s_waitcnt lgkmcnt(0)" ::: "memory");
    const int rswz = (lr & 7) << 4;
    bf16x8 pa[2][2];
#pragma unroll
    for (int g = 0; g < 2; ++g) {
      pa[g][0] = *(const bf16x8*)(Plds[w][g] + lr * 128 + ((lg * 16) ^ rswz));
      pa[g][1] = *(const bf16x8*)(Plds[w][g] + lr * 128 + ((64 + lg * 16) ^ rswz));
    }
#pragma unroll
    for (int d = 0; d < 5; ++d) {
      bf16x8 v0 = *(const bf16x8*)&Vh[(size_t)(d * 16 + lr) * SS + kv0 + lg * 8];
      bf16x8 v1 = *(const bf16x8*)&Vh[(size_t)(d * 16 + lr) * SS + kv0 + 32 + lg * 8];
#pragma unroll
      for (int g = 0; g < 2; ++g) {
        oacc[g][d] = __builtin_amdgcn_mfma_f32_16x16x32_bf16(pa[g][0], v0, oacc[g][d], 0, 0, 0);
        oacc[g][d] = __builtin_amdgcn_mfma_f32_16x16x32_bf16(pa[g][1], v1, oacc[g][d], 0, 0, 0);
      }
    }
  }
  const int b = bh >> 5, h = bh & 31;
#pragma unroll
  for (int g = 0; g < 2; ++g)
#pragma unroll
    for (int r = 0; r < 4; ++r) {
      const int qr = q0 + g * 16 + lg * 4 + r;
      const float inv = 1.f / lrow[g][r];
#pragma unroll
      for (int d = 0; d < 5; ++d)
        O[(size_t)(b * SS + qr) * DD + h * DHH + d * 16 + lr] = f2bf(oacc[g][d][r] * inv);
    }
}

__device__ __forceinline__ float gelu_f(float x) {
  float x3 = x * x * x;
  return 0.5f * x * (1.f + tanhf(0.7978845608028654f * (x + 0.044715f * x3)));
}

// ---------------- 256x256 GEMM (verified best config): 8 waves, BK=64, 8-phase counted-vmcnt ----------------
template <int MODE>
__global__ __launch_bounds__(512, 2) void gemm256(const unsigned short* __restrict__ A,
                                                  const unsigned short* __restrict__ Bt,
                                                  const float* __restrict__ bias,
                                                  void* __restrict__ Cout,
                                                  const unsigned short* __restrict__ addb,
                                                  const float* __restrict__ addf,
                                                  int M, int N, int K, int nby) {
  __shared__ __align__(16) char lds[131072];

  const int bid = blockIdx.x;
  const int by = bid % nby, bx = bid / nby;   // column-major: A-panel L2 reuse
  const int m0 = by * 256, n0 = bx * 256;

  const int tid = threadIdx.x;
  const int w = tid >> 6, lane = tid & 63;
  const int lr = lane & 15, lg = lane >> 4;
  const int wm = w >> 2, wn = w & 3;

  const int srow = w * 16 + (lane >> 3);
  const int scol = ((lane & 7) ^ ((lane >> 3) & 7)) * 8;
  const unsigned short* pA = A  + (size_t)(m0 + srow) * K + scol;
  const unsigned short* pB = Bt + (size_t)(n0 + srow) * K + scol;
  const int wdst = w * 2048;

  const int rdA = wm * 16384 + lr * 128;
  const int rdB = 65536 + (wn >> 1) * 16384 + ((wn & 1) * 64 + lr) * 128;
  const int sl0 = ((lg) ^ (lr & 7)) << 4;
  const int sl1 = ((4 + lg) ^ (lr & 7)) << 4;

  f32x4 acc[8][4];
#pragma unroll
  for (int i = 0; i < 8; ++i)
#pragma unroll
    for (int j = 0; j < 4; ++j) acc[i][j] = (f32x4){0.f, 0.f, 0.f, 0.f};

  const int nt = K >> 6;

#define RA(BUF, m, kh) (*(const bf16x8*)(lds + (BUF) + rdA + (m) * 2048 + ((kh) ? sl1 : sl0)))
#define RB(BUF, n, kh) (*(const bf16x8*)(lds + (BUF) + rdB + (n) * 2048 + ((kh) ? sl1 : sl0)))
#define STGA(dt, h, DST)                                                       \
  { const unsigned short* s_ = pA + (size_t)(dt) * 64 + (size_t)(h) * 128 * K; \
    gl_lds16(s_,                 lds + (DST) + wdst);                          \
    gl_lds16(s_ + (size_t)8 * K, lds + (DST) + wdst + 1024); }
#define STGB(dt, h, DST)                                                       \
  { const unsigned short* s_ = pB + (size_t)(dt) * 64 + (size_t)(h) * 128 * K; \
    gl_lds16(s_,                 lds + 65536 + (DST) + wdst);                  \
    gl_lds16(s_ + (size_t)8 * K, lds + 65536 + (DST) + wdst + 1024); }
#define BARR __builtin_amdgcn_s_barrier()
#define MFMA8x2(AV, BV, MB, NB)                                              \
  __builtin_amdgcn_s_setprio(1);                                             \
  _Pragma("unroll") for (int kh_ = 0; kh_ < 2; ++kh_)                        \
  _Pragma("unroll") for (int m_ = 0; m_ < 4; ++m_)                           \
  _Pragma("unroll") for (int n_ = 0; n_ < 2; ++n_)                           \
    acc[(MB) + m_][(NB) + n_] = __builtin_amdgcn_mfma_f32_16x16x32_bf16(     \
        AV[m_][kh_], BV[n_][kh_], acc[(MB) + m_][(NB) + n_], 0, 0, 0);       \
  __builtin_amdgcn_s_setprio(0);

  STGA(0, 0, 0);
  STGA(0, 1, 16384);
  STGB(0, 0, 0);
  STGB(0, 1, 16384);
  STGA(1, 0, 32768);
  STGA(1, 1, 32768 + 16384);
  STGB(1, 0, 32768);
  asm volatile("s_waitcnt vmcnt(6)" ::: "memory");
  BARR;
  __builtin_amdgcn_sched_barrier(0);

  for (int t = 0; t < nt; t += 2) {
    const bool more = (t + 2 < nt);
    bf16x8 avL[4][2], avH[4][2], bvL[2][2], bvH[2][2];

#pragma unroll
    for (int m_ = 0; m_ < 4; ++m_) { avL[m_][0] = RA(0, m_, 0); avL[m_][1] = RA(0, m_, 1); }
#pragma unroll
    for (int n_ = 0; n_ < 2; ++n_) { bvL[n_][0] = RB(0, n_, 0); bvL[n_][1] = RB(0, n_, 1); }
    STGB(1, 1, 32768 + 16384);
    BARR;
    MFMA8x2(avL, bvL, 0, 0);
    BARR;
#pragma unroll
    for (int m_ = 0; m_ < 4; ++m_) { avH[m_][0] = RA(0, 4 + m_, 0); avH[m_][1] = RA(0, 4 + m_, 1); }
    BARR;
    MFMA8x2(avH, bvL, 4, 0);
    BARR;
#pragma unroll
    for (int n_ = 0; n_ < 2; ++n_) { bvH[n_][0] = RB(0, 2 + n_, 0); bvH[n_][1] = RB(0, 2 + n_, 1); }
    if (more) STGA(2, 0, 0);
    BARR;
    MFMA8x2(avH, bvH, 4, 2);
    BARR;
    if (more) STGA(2, 1, 16384);
    BARR;
    MFMA8x2(avL, bvH, 0, 2);
    if (more) { asm volatile("s_waitcnt vmcnt(4)" ::: "memory"); }
    else      { asm volatile("s_waitcnt vmcnt(0)" ::: "memory"); }
    BARR;
    __builtin_amdgcn_sched_barrier(0);

#pragma unroll
    for (int m_ = 0; m_ < 4; ++m_) { avL[m_][0] = RA(32768, m_, 0); avL[m_][1] = RA(32768, m_, 1); }
#pragma unroll
    for (int n_ = 0; n_ < 2; ++n_) { bvL[n_][0] = RB(32768, n_, 0); bvL[n_][1] = RB(32768, n_, 1); }
    if (more) STGB(2, 0, 0);
    BARR;
    MFMA8x2(avL, bvL, 0, 0);
    BARR;
#pragma unroll
    for (int m_ = 0; m_ < 4; ++m_) { avH[m_][0] = RA(32768, 4 + m_, 0); avH[m_][1] = RA(32768, 4 + m_, 1); }
    if (more) STGB(2, 1, 16384);
    BARR;
    MFMA8x2(avH, bvL, 4, 0);
    BARR;
#pragma unroll
    for (int n_ = 0; n_ < 2; ++n_) { bvH[n_][0] = RB(32768, 2 + n_, 0); bvH[n_][1] = RB(32768, 2 + n_, 1); }
    if (more) STGA(3, 0, 32768);
    BARR;
    MFMA8x2(avH, bvH, 4, 2);
    BARR;
    if (more) { STGA(3, 1, 32768 + 16384); STGB(3, 0, 32768); }
    BARR;
    MFMA8x2(avL, bvH, 0, 2);
    if (more) { asm volatile("s_waitcnt vmcnt(6)" ::: "memory"); }
    BARR;
    __builtin_amdgcn_sched_barrier(0);

    pA += 128; pB += 128;
  }
#undef RA
#undef RB
#undef STGA
#undef STGB
#undef BARR
#undef MFMA8x2

#pragma unroll
  for (int m = 0; m < 8; ++m) {
    const int rb = m0 + wm * 128 + m * 16 + lg * 4;
#pragma unroll
    for (int n = 0; n < 4; ++n) {
      const int col = n0 + wn * 64 + n * 16 + lr;
      const float bv = bias[col];
#pragma unroll
      for (int r = 0; r < 4; ++r) {
        const size_t idx = (size_t)(rb + r) * N + col;
        float v = acc[m][n][r] + bv;
        if (MODE == 2) v = gelu_f(v);
        if (MODE == 3) {
          ((float*)Cout)[idx] = v + bf2f(addb[idx]) + addf[idx];
        } else {
          ((unsigned short*)Cout)[idx] = f2bf(v);
        }
      }
    }
  }
}

extern "C" void kernel_launch(void* const* d_in, const int* in_sizes, int n_in,
                              void* d_out, int out_size, void* d_ws, size_t ws_size,
                              hipStream_t stream) {
  (void)in_sizes; (void)n_in; (void)out_size; (void)ws_size;
  const float* hidden = (const float*)d_in[1];
  const float* ln_g = (const float*)d_in[2];
  const float* ln_b = (const float*)d_in[3];
  const float* wqkv = (const float*)d_in[4];
  const float* bqkv = (const float*)d_in[5];
  const float* wout = (const float*)d_in[6];
  const float* bout = (const float*)d_in[7];
  const float* wfc1 = (const float*)d_in[8];
  const float* bfc1 = (const float*)d_in[9];
  const float* wfc2 = (const float*)d_in[10];
  const float* bfc2 = (const float*)d_in[11];
  float* out = (float*)d_out;

  char* ws = (char*)d_ws;
  size_t off = 0;
  auto alloc = [&](size_t bytes) -> void* {
    void* p = ws + off;
    off += (bytes + 255) & ~(size_t)255;
    return p;
  };
  unsigned short* wqkvT = (unsigned short*)alloc((size_t)3 * DD * DD * 2);
  unsigned short* woutT = (unsigned short*)alloc((size_t)DD * DD * 2);
  unsigned short* wfc1T = (unsigned short*)alloc((size_t)NII * DD * 2);
  unsigned short* wfc2T = (unsigned short*)alloc((size_t)DD * NII * 2);
  unsigned short* xln   = (unsigned short*)alloc((size_t)NTOK * DD * 2);
  unsigned short* regA  = (unsigned short*)alloc((size_t)NTOK * NII * 2);  // qkv, then h1
  unsigned short* Qp    = (unsigned short*)alloc((size_t)2 * HH * SS * DPAD * 2);  // then attn_proj
  unsigned short* Kp    = (unsigned short*)alloc((size_t)2 * HH * SS * DPAD * 2);
  unsigned short* Vt    = (unsigned short*)alloc((size_t)2 * HH * DHH * SS * 2);
  unsigned short* Obuf  = (unsigned short*)alloc((size_t)NTOK * DD * 2);
  unsigned short* qkvbuf   = regA;
  unsigned short* h1       = regA;
  unsigned short* attnproj = Qp;

  wt_transpose_all<<<dim3(19200), 256, 0, stream>>>(wqkv, wout, wfc1, wfc2,
                                                    wqkvT, woutT, wfc1T, wfc2T);
  ln_kernel<<<NTOK, 256, 0, stream>>>(hidden, ln_g, ln_b, xln);
  gemm256<0><<<dim3((3 * DD / 256) * (NTOK / 256)), 512, 0, stream>>>(
      xln, wqkvT, bqkv, qkvbuf, nullptr, nullptr, NTOK, 3 * DD, DD, NTOK / 256);
  rope_kernel<<<NTOK, 256, 0, stream>>>(qkvbuf, Qp, Kp, Vt);
  attn_kernel<<<dim3(2048), 128, 0, stream>>>(Qp, Kp, Vt, Obuf);
  gemm256<0><<<dim3((DD / 256) * (NTOK / 256)), 512, 0, stream>>>(
      Obuf, woutT, bout, attnproj, nullptr, nullptr, NTOK, DD, DD, NTOK / 256);
  gemm256<2><<<dim3((NII / 256) * (NTOK / 256)), 512, 0, stream>>>(
      xln, wfc1T, bfc1, h1, nullptr, nullptr, NTOK, NII, DD, NTOK / 256);
  gemm256<3><<<dim3((DD / 256) * (NTOK / 256)), 512, 0, stream>>>(
      h1, wfc2T, bfc2, out, attnproj, hidden, NTOK, DD, NII, NTOK / 256);
}